// Round 1
// baseline (9098.268 us; speedup 1.0000x reference)
//
#include <hip/hip_runtime.h>
#include <hip/hip_fp16.h>

#define HC 16
#define CIN 16
#define BD 31
#define HH 128
#define WW 128
#define PLANE (HH*WW)           // 16384
#define CH_STRIDE (BD*PLANE)    // 507904

__device__ __forceinline__ float sigmoidf_fast(float x) {
    return 1.0f / (1.0f + __expf(-x));
}
__device__ __forceinline__ float tanhf_fast(float x) {
    return 2.0f / (1.0f + __expf(-2.0f * x)) - 1.0f;
}

// Kernel 1: 3x3x3 SAME conv (CIN=16 -> 32 gates), tanh/sigmoid activations,
// store packed half2(z,f) into the output buffer (reused as scratch).
// Block: 256 threads; tile = 16(H) x 64(W) for one (b,d); thread owns 4 H-rows
// x all 32 output channels (128 fp32 accumulators).
__global__ __launch_bounds__(256, 2)
void conv_gates_kernel(const float* __restrict__ inp,
                       const float* __restrict__ cw,
                       __half2* __restrict__ zf)
{
    __shared__ __align__(16) float wlds[CIN * 27 * 32];  // [ci][tap][co], 55.3 KB
    for (int idx = threadIdx.x; idx < CIN * 27 * 32; idx += 256) {
        int co   = idx & 31;
        int rest = idx >> 5;
        int tap  = rest % 27;
        int ci   = rest / 27;
        wlds[idx] = cw[(co * CIN + ci) * 27 + tap];
    }
    __syncthreads();

    int x  = blockIdx.x;
    int wt = x & 1;  x >>= 1;
    int ht = x & 7;  x >>= 3;
    int d  = x % BD; x /= BD;
    int b  = x;

    int w  = wt * 64 + (threadIdx.x & 63);
    int hb = ht * 16 + (threadIdx.x >> 6) * 4;

    float acc[4][32];
    #pragma unroll
    for (int r = 0; r < 4; ++r)
        #pragma unroll
        for (int c = 0; c < 32; ++c) acc[r][c] = 0.f;

    const float* ib = inp + (size_t)b * CIN * CH_STRIDE;

    #pragma unroll 1
    for (int ci = 0; ci < CIN; ++ci) {
        const float* ibc = ib + ci * CH_STRIDE;
        #pragma unroll 1
        for (int kd = 0; kd < 3; ++kd) {
            int dd = d + kd - 1;
            if (dd < 0 || dd >= BD) continue;   // uniform per-block branch
            const float* ip = ibc + dd * PLANE;
            #pragma unroll
            for (int kh = 0; kh < 3; ++kh) {
                #pragma unroll
                for (int kw = 0; kw < 3; ++kw) {
                    int win = w + kw - 1;
                    bool wv = (unsigned)win < WW;
                    float xv[4];
                    #pragma unroll
                    for (int r = 0; r < 4; ++r) {
                        int hin = hb + r + kh - 1;
                        bool hv = (unsigned)hin < HH;
                        xv[r] = (wv && hv) ? ip[hin * WW + win] : 0.f;
                    }
                    const float4* wp =
                        (const float4*)&wlds[((ci * 27) + (kd * 9 + kh * 3 + kw)) * 32];
                    #pragma unroll
                    for (int q = 0; q < 8; ++q) {
                        float4 wq = wp[q];
                        #pragma unroll
                        for (int r = 0; r < 4; ++r) {
                            acc[r][q * 4 + 0] += xv[r] * wq.x;
                            acc[r][q * 4 + 1] += xv[r] * wq.y;
                            acc[r][q * 4 + 2] += xv[r] * wq.z;
                            acc[r][q * 4 + 3] += xv[r] * wq.w;
                        }
                    }
                }
            }
        }
    }

    #pragma unroll
    for (int r = 0; r < 4; ++r) {
        int hh = hb + r;
        #pragma unroll
        for (int c = 0; c < HC; ++c) {
            float z = tanhf_fast(acc[r][c]);
            float f = sigmoidf_fast(acc[r][c + HC]);
            size_t o = ((size_t)(b * HC + c) * BD + d) * PLANE + hh * WW + w;
            zf[o] = __floats2half2_rn(z, f);
        }
    }
}

// Kernel 2: fused scan over D + MLP head. One thread per (b,h,w) column.
// Reads half2(z,f) from the out buffer, overwrites each consumed slot with the
// final float result. Register double-buffer for the next d's z/f loads.
__global__ __launch_bounds__(256)
void scan_mlp_kernel(float* out,
                     const float* __restrict__ w1,
                     const float* __restrict__ w2,
                     const float* __restrict__ w3,
                     const int* __restrict__ rev_p)
{
    int tid = blockIdx.x * 256 + threadIdx.x;
    int b   = tid >> 14;          // 16384 pixels per batch
    int pix = tid & 16383;
    int h   = pix >> 7;
    int w   = pix & 127;
    int rev = rev_p[0];

    const unsigned* zfw = (const unsigned*)out;
    size_t cbase = (size_t)b * HC * CH_STRIDE + h * WW + w;

    float hreg[16];
    #pragma unroll
    for (int c = 0; c < 16; ++c) hreg[c] = 0.f;

    // prefetch first d
    int d0 = rev ? (BD - 1) : 0;
    unsigned nz[16];
    {
        size_t bs = cbase + (size_t)d0 * PLANE;
        #pragma unroll
        for (int c = 0; c < 16; ++c) nz[c] = zfw[bs + (size_t)c * CH_STRIDE];
    }

    #pragma unroll 1
    for (int dd = 0; dd < BD; ++dd) {
        unsigned cz[16];
        #pragma unroll
        for (int c = 0; c < 16; ++c) cz[c] = nz[c];

        int d = rev ? (BD - 1 - dd) : dd;
        size_t base = cbase + (size_t)d * PLANE;

        if (dd + 1 < BD) {
            int dn = rev ? (BD - 2 - dd) : (dd + 1);
            size_t bn = cbase + (size_t)dn * PLANE;
            #pragma unroll
            for (int c = 0; c < 16; ++c) nz[c] = zfw[bn + (size_t)c * CH_STRIDE];
        }

        // recurrence: h = f*h + (1-f)*z
        #pragma unroll
        for (int c = 0; c < 16; ++c) {
            __half2 v = *(__half2*)&cz[c];
            float z = __low2float(v);
            float f = __high2float(v);
            hreg[c] = f * hreg[c] + (1.f - f) * z;
        }

        // MLP head: y = gelu(x@w1)@w2 + (x@w3)[:16] * sigmoid((x@w3)[16:])
        float g1[32];
        #pragma unroll
        for (int j = 0; j < 32; ++j) {
            float s = 0.f;
            #pragma unroll
            for (int k = 0; k < 16; ++k) s += hreg[k] * w1[k * 32 + j];
            g1[j] = 0.5f * s * (1.f + erff(s * 0.70710678118f));
        }
        float x1[16];
        #pragma unroll
        for (int c = 0; c < 16; ++c) {
            float s = 0.f;
            #pragma unroll
            for (int j = 0; j < 32; ++j) s += g1[j] * w2[j * 16 + c];
            x1[c] = s;
        }
        #pragma unroll
        for (int c = 0; c < 16; ++c) {
            float a = 0.f, wg = 0.f;
            #pragma unroll
            for (int k = 0; k < 16; ++k) {
                a  += hreg[k] * w3[k * 32 + c];
                wg += hreg[k] * w3[k * 32 + 16 + c];
            }
            float y = x1[c] + a * sigmoidf_fast(wg);
            out[base + (size_t)c * CH_STRIDE] = y;
        }
    }
}

extern "C" void kernel_launch(void* const* d_in, const int* in_sizes, int n_in,
                              void* d_out, int out_size, void* d_ws, size_t ws_size,
                              hipStream_t stream)
{
    const float* inp = (const float*)d_in[0];
    const float* cw  = (const float*)d_in[1];
    const float* w1  = (const float*)d_in[2];
    const float* w2  = (const float*)d_in[3];
    const float* w3  = (const float*)d_in[4];
    const int*   rev = (const int*)d_in[5];

    // conv: grid = wtiles(2) * htiles(8) * D(31) * B(4) = 1984 blocks
    conv_gates_kernel<<<dim3(2 * 8 * 31 * 4), dim3(256), 0, stream>>>(
        inp, cw, (__half2*)d_out);

    // scan+mlp: 4*128*128 = 65536 threads
    scan_mlp_kernel<<<dim3(65536 / 256), dim3(256), 0, stream>>>(
        (float*)d_out, w1, w2, w3, rev);
}

// Round 2
// 1353.173 us; speedup vs baseline: 6.7237x; 6.7237x over previous
//
#include <hip/hip_runtime.h>
#include <hip/hip_fp16.h>

#define HC 16
#define CIN 16
#define BD 31
#define HH 128
#define WW 128
#define PLANE (HH*WW)           // 16384
#define CH_STRIDE (BD*PLANE)    // 507904

__device__ __forceinline__ float sigmoidf_fast(float x) {
    return 1.0f / (1.0f + __expf(-x));
}
__device__ __forceinline__ float tanhf_fast(float x) {
    return 2.0f / (1.0f + __expf(-2.0f * x)) - 1.0f;
}

// Kernel 1: 3x3x3 SAME conv (CIN=16 -> 32 gates), tanh/sigmoid activations,
// store packed half2(z,f) into the output buffer (reused as scratch).
// Block: 256 threads; tile = 16(H) x 64(W) for one (b,d); thread owns 4 H-rows
// x all 32 output channels (128 fp32 accumulators).
// NOTE: launch_bounds min-waves=1 — with (256,2) the 128-VGPR cap spilled all
// 128 accumulators to scratch (12GB fetch / 21GB write observed in rocprof).
__global__ __launch_bounds__(256, 1)
void conv_gates_kernel(const float* __restrict__ inp,
                       const float* __restrict__ cw,
                       __half2* __restrict__ zf)
{
    __shared__ __align__(16) float wlds[CIN * 27 * 32];  // [ci][tap][co], 55.3 KB
    for (int idx = threadIdx.x; idx < CIN * 27 * 32; idx += 256) {
        int co   = idx & 31;
        int rest = idx >> 5;
        int tap  = rest % 27;
        int ci   = rest / 27;
        wlds[idx] = cw[(co * CIN + ci) * 27 + tap];
    }
    __syncthreads();

    int x  = blockIdx.x;
    int wt = x & 1;  x >>= 1;
    int ht = x & 7;  x >>= 3;
    int d  = x % BD; x /= BD;
    int b  = x;

    int w  = wt * 64 + (threadIdx.x & 63);
    int hb = ht * 16 + (threadIdx.x >> 6) * 4;

    float acc[4][32];
    #pragma unroll
    for (int r = 0; r < 4; ++r)
        #pragma unroll
        for (int c = 0; c < 32; ++c) acc[r][c] = 0.f;

    const float* ib = inp + (size_t)b * CIN * CH_STRIDE;

    #pragma unroll 1
    for (int ci = 0; ci < CIN; ++ci) {
        const float* ibc = ib + ci * CH_STRIDE;
        #pragma unroll 1
        for (int kd = 0; kd < 3; ++kd) {
            int dd = d + kd - 1;
            if (dd < 0 || dd >= BD) continue;   // uniform per-block branch
            const float* ip = ibc + dd * PLANE;
            #pragma unroll
            for (int kh = 0; kh < 3; ++kh) {
                #pragma unroll
                for (int kw = 0; kw < 3; ++kw) {
                    int win = w + kw - 1;
                    bool wv = (unsigned)win < WW;
                    float xv[4];
                    #pragma unroll
                    for (int r = 0; r < 4; ++r) {
                        int hin = hb + r + kh - 1;
                        bool hv = (unsigned)hin < HH;
                        xv[r] = (wv && hv) ? ip[hin * WW + win] : 0.f;
                    }
                    const float4* wp =
                        (const float4*)&wlds[((ci * 27) + (kd * 9 + kh * 3 + kw)) * 32];
                    #pragma unroll
                    for (int q = 0; q < 8; ++q) {
                        float4 wq = wp[q];
                        #pragma unroll
                        for (int r = 0; r < 4; ++r) {
                            acc[r][q * 4 + 0] += xv[r] * wq.x;
                            acc[r][q * 4 + 1] += xv[r] * wq.y;
                            acc[r][q * 4 + 2] += xv[r] * wq.z;
                            acc[r][q * 4 + 3] += xv[r] * wq.w;
                        }
                    }
                }
            }
        }
    }

    #pragma unroll
    for (int r = 0; r < 4; ++r) {
        int hh = hb + r;
        #pragma unroll
        for (int c = 0; c < HC; ++c) {
            float z = tanhf_fast(acc[r][c]);
            float f = sigmoidf_fast(acc[r][c + HC]);
            size_t o = ((size_t)(b * HC + c) * BD + d) * PLANE + hh * WW + w;
            zf[o] = __floats2half2_rn(z, f);
        }
    }
}

// Kernel 2: scan over D only. One thread per (b,h,w) column; reads half2(z,f)
// from the out buffer and overwrites each consumed 4B slot with fp32 h.
__global__ __launch_bounds__(256)
void scan_kernel(float* out, const int* __restrict__ rev_p)
{
    int tid = blockIdx.x * 256 + threadIdx.x;
    int b   = tid >> 14;          // PLANE = 16384 pixels per batch
    int pix = tid & 16383;
    int rev = rev_p[0];

    const unsigned* zfw = (const unsigned*)out;
    size_t cbase = (size_t)b * HC * CH_STRIDE + pix;

    float hreg[16];
    #pragma unroll
    for (int c = 0; c < 16; ++c) hreg[c] = 0.f;

    int d0 = rev ? (BD - 1) : 0;
    unsigned nz[16];
    {
        size_t bs = cbase + (size_t)d0 * PLANE;
        #pragma unroll
        for (int c = 0; c < 16; ++c) nz[c] = zfw[bs + (size_t)c * CH_STRIDE];
    }

    #pragma unroll 1
    for (int dd = 0; dd < BD; ++dd) {
        unsigned cz[16];
        #pragma unroll
        for (int c = 0; c < 16; ++c) cz[c] = nz[c];

        int d = rev ? (BD - 1 - dd) : dd;
        size_t base = cbase + (size_t)d * PLANE;

        if (dd + 1 < BD) {
            int dn = rev ? (BD - 2 - dd) : (dd + 1);
            size_t bn = cbase + (size_t)dn * PLANE;
            #pragma unroll
            for (int c = 0; c < 16; ++c) nz[c] = zfw[bn + (size_t)c * CH_STRIDE];
        }

        #pragma unroll
        for (int c = 0; c < 16; ++c) {
            __half2 v = *(__half2*)&cz[c];
            float z = __low2float(v);
            float f = __high2float(v);
            hreg[c] = f * hreg[c] + (1.f - f) * z;
            out[base + (size_t)c * CH_STRIDE] = hreg[c];   // fp32 h in place
        }
    }
}

// Kernel 3: MLP head, one thread per (b,d,pixel) point. Reads fp32 h from the
// out buffer (16 channel-strided floats), overwrites with final y in place.
// Weights staged transposed in LDS, read as float4 broadcasts.
__global__ __launch_bounds__(256)
void mlp_kernel(float* out,
                const float* __restrict__ w1,
                const float* __restrict__ w2,
                const float* __restrict__ w3)
{
    __shared__ __align__(16) float w1t[32][16];  // w1t[j][k] = w1[k][j]
    __shared__ __align__(16) float w3t[32][16];  // w3t[j][k] = w3[k][j]
    __shared__ __align__(16) float w2t[16][32];  // w2t[c][j] = w2[j][c]

    int t = threadIdx.x;
    for (int i = t; i < 512; i += 256) {
        int j = i >> 4, k = i & 15;
        w1t[j][k] = w1[k * 32 + j];
        w3t[j][k] = w3[k * 32 + j];
    }
    for (int i = t; i < 512; i += 256) {
        int c = i >> 5, j = i & 31;
        w2t[c][j] = w2[j * 16 + c];
    }
    __syncthreads();

    int tid  = blockIdx.x * 256 + t;
    int pix  = tid & 16383;
    int rest = tid >> 14;         // b*31 + d
    int b    = rest / BD;
    int d    = rest % BD;

    size_t base = (size_t)b * HC * CH_STRIDE + (size_t)d * PLANE + pix;

    float h[16];
    #pragma unroll
    for (int c = 0; c < 16; ++c) h[c] = out[base + (size_t)c * CH_STRIDE];

    float g1[32];
    #pragma unroll
    for (int j = 0; j < 32; ++j) {
        const float4* wp = (const float4*)w1t[j];
        float s = 0.f;
        #pragma unroll
        for (int q = 0; q < 4; ++q) {
            float4 wq = wp[q];
            s += h[q * 4 + 0] * wq.x + h[q * 4 + 1] * wq.y +
                 h[q * 4 + 2] * wq.z + h[q * 4 + 3] * wq.w;
        }
        g1[j] = 0.5f * s * (1.f + erff(s * 0.70710678118f));
    }

    float x1[16];
    #pragma unroll
    for (int c = 0; c < 16; ++c) {
        const float4* wp = (const float4*)w2t[c];
        float s = 0.f;
        #pragma unroll
        for (int q = 0; q < 8; ++q) {
            float4 wq = wp[q];
            s += g1[q * 4 + 0] * wq.x + g1[q * 4 + 1] * wq.y +
                 g1[q * 4 + 2] * wq.z + g1[q * 4 + 3] * wq.w;
        }
        x1[c] = s;
    }

    #pragma unroll
    for (int c = 0; c < 16; ++c) {
        const float4* wa = (const float4*)w3t[c];
        const float4* wb = (const float4*)w3t[c + 16];
        float a = 0.f, wg = 0.f;
        #pragma unroll
        for (int q = 0; q < 4; ++q) {
            float4 qa = wa[q], qb = wb[q];
            a  += h[q * 4 + 0] * qa.x + h[q * 4 + 1] * qa.y +
                  h[q * 4 + 2] * qa.z + h[q * 4 + 3] * qa.w;
            wg += h[q * 4 + 0] * qb.x + h[q * 4 + 1] * qb.y +
                  h[q * 4 + 2] * qb.z + h[q * 4 + 3] * qb.w;
        }
        out[base + (size_t)c * CH_STRIDE] = x1[c] + a * sigmoidf_fast(wg);
    }
}

extern "C" void kernel_launch(void* const* d_in, const int* in_sizes, int n_in,
                              void* d_out, int out_size, void* d_ws, size_t ws_size,
                              hipStream_t stream)
{
    const float* inp = (const float*)d_in[0];
    const float* cw  = (const float*)d_in[1];
    const float* w1  = (const float*)d_in[2];
    const float* w2  = (const float*)d_in[3];
    const float* w3  = (const float*)d_in[4];
    const int*   rev = (const int*)d_in[5];

    // conv: grid = wtiles(2) * htiles(8) * D(31) * B(4) = 1984 blocks
    conv_gates_kernel<<<dim3(2 * 8 * 31 * 4), dim3(256), 0, stream>>>(
        inp, cw, (__half2*)d_out);

    // scan: 4*128*128 = 65536 column threads
    scan_kernel<<<dim3(65536 / 256), dim3(256), 0, stream>>>(
        (float*)d_out, rev);

    // mlp: 4*31*16384 = 2031616 point threads
    mlp_kernel<<<dim3(4 * BD * PLANE / 256), dim3(256), 0, stream>>>(
        (float*)d_out, w1, w2, w3);
}

// Round 3
// 343.314 us; speedup vs baseline: 26.5013x; 3.9415x over previous
//
#include <hip/hip_runtime.h>
#include <hip/hip_fp16.h>

#define HC 16
#define CIN 16
#define BD 31
#define HH 128
#define WW 128
#define PLANE (HH*WW)           // 16384
#define CH_STRIDE (BD*PLANE)    // 507904

typedef __attribute__((ext_vector_type(8))) short bf16x8;   // 8 bf16 = 4 VGPR
typedef __attribute__((ext_vector_type(16))) float f32x16;  // MFMA 32x32 acc

__device__ __forceinline__ float sigmoidf_fast(float x) {
    return 1.0f / (1.0f + __expf(-x));
}
__device__ __forceinline__ float tanhf_fast(float x) {
    return 2.0f / (1.0f + __expf(-2.0f * x)) - 1.0f;
}
__device__ __forceinline__ ushort f2bf(float f) {   // RNE float->bf16
    unsigned u = __float_as_uint(f);
    u = (u + 0x7fffu + ((u >> 16) & 1u)) >> 16;
    return (ushort)u;
}

// ---------------------------------------------------------------------------
// Weight prep: arrange conv weights into per-lane MFMA A-fragments in d_ws.
// wtab[kd][tap][lane][j] (bf16): co = lane&31, ci = 8*(lane>>5)+j.
// The same (lane,j)->ci map is used for the B fragment, so the result is
// invariant to the HW's actual k-slot ordering (shared k-permutation).
// ---------------------------------------------------------------------------
__global__ void wprep_kernel(const float* __restrict__ cw, ushort* __restrict__ wtab)
{
    int idx = blockIdx.x * 256 + threadIdx.x;
    if (idx >= 3 * 9 * 64 * 8) return;
    int j    = idx & 7;
    int lane = (idx >> 3) & 63;
    int t    = (idx >> 9) % 9;
    int kd   = (idx >> 9) / 9;
    int co = lane & 31;
    int ci = 8 * (lane >> 5) + j;
    int kh = t / 3, kw = t % 3;
    wtab[idx] = f2bf(cw[(co * CIN + ci) * 27 + kd * 9 + kh * 3 + kw]);
}

// ---------------------------------------------------------------------------
// Conv via MFMA implicit GEMM. Block = 256 thr (4 waves), tile = one (b,d),
// 4 H-rows x 128 W. Wave w owns row w: 4 n-tiles of 32 w, acc = 4x f32x16.
// kd outer loop: stage one input d-plane slab [6 rows][132 wcol][16 ci] bf16
// in LDS, then 9 (kh,kw) taps x 4 tiles of v_mfma_f32_32x32x16_bf16.
// LDS XOR swizzle (bits 4-6 ^= wcol[3:1]) breaks the 32B-stride bank conflict;
// map is injective (verified bit-level) and applied on both write and read.
// ---------------------------------------------------------------------------
#define SLAB_BYTES (6 * 132 * 32)   // 25344 B

__device__ __forceinline__ unsigned slab_byte(int row, int wcol, int cioff) {
    unsigned b = (unsigned)(row * 4224 + wcol * 32 + cioff);
    return b ^ ((unsigned)(wcol & 0xE) << 3);
}

__global__ __launch_bounds__(256, 3)
void conv_gates_mfma(const float* __restrict__ inp,
                     const ushort* __restrict__ wtab,
                     __half2* __restrict__ zf)
{
    __shared__ __align__(16) char slab[SLAB_BYTES];

    // XCD-aware swizzle (3968 = 8*496): consecutive (b,d,ht) share an XCD's L2
    // so the 3x d-plane re-reads mostly hit L2.
    int p = blockIdx.x;
    int logical = (p & 7) * 496 + (p >> 3);
    int ht = logical & 31;          // 32 h-tiles of 4 rows
    int g  = logical >> 5;
    int d  = g % BD;
    int b  = g / BD;
    int h0 = ht * 4;

    int lane = threadIdx.x & 63;
    int wid  = threadIdx.x >> 6;
    int wl   = lane & 31;
    int cio  = (lane >> 5) * 16;

    f32x16 acc[4];
    #pragma unroll
    for (int n = 0; n < 4; ++n)
        #pragma unroll
        for (int r = 0; r < 16; ++r) acc[n][r] = 0.f;

    const bf16x8* wt = (const bf16x8*)wtab;

    #pragma unroll 1
    for (int kd = 0; kd < 3; ++kd) {
        int dd = d + kd - 1;
        if (dd < 0 || dd >= BD) continue;   // uniform per block

        __syncthreads();
        // stage slab: 6 rows x 132 wcols x 16 ci, as b64 chunks of 4 ci
        #pragma unroll 1
        for (int it = threadIdx.x; it < 6 * 132 * 4; it += 256) {
            int q    = it & 3;              // ci quad
            int rest = it >> 2;
            int wcol = rest % 132;
            int row  = rest / 132;
            int h = h0 + row - 1;
            int w = wcol - 1;
            float v0 = 0.f, v1 = 0.f, v2 = 0.f, v3 = 0.f;
            if ((unsigned)h < HH && (unsigned)w < WW) {
                const float* pin = inp
                    + ((size_t)(b * CIN + q * 4) * BD + dd) * PLANE + h * WW + w;
                v0 = pin[0];
                v1 = pin[CH_STRIDE];
                v2 = pin[2 * CH_STRIDE];
                v3 = pin[3 * CH_STRIDE];
            }
            uint2 pk;
            pk.x = (unsigned)f2bf(v0) | ((unsigned)f2bf(v1) << 16);
            pk.y = (unsigned)f2bf(v2) | ((unsigned)f2bf(v3) << 16);
            *(uint2*)(slab + slab_byte(row, wcol, q * 8)) = pk;
        }
        __syncthreads();

        // A fragments for this kd (L2-broadcast reads)
        bf16x8 af[9];
        #pragma unroll
        for (int t = 0; t < 9; ++t)
            af[t] = wt[(kd * 9 + t) * 64 + lane];

        #pragma unroll
        for (int t = 0; t < 9; ++t) {
            int dh = t / 3 - 1;
            int dw = t % 3 - 1;
            int row = wid + 1 + dh;
            #pragma unroll
            for (int n = 0; n < 4; ++n) {
                int wcol = n * 32 + wl + 1 + dw;
                bf16x8 bf = *(const bf16x8*)(slab + slab_byte(row, wcol, cio));
                acc[n] = __builtin_amdgcn_mfma_f32_32x32x16_bf16(af[t], bf, acc[n], 0, 0, 0);
            }
        }
    }

    // epilogue: C/D map (verified): col = lane&31, row = (reg&3)+8*(reg>>2)+4*(lane>>5)
    // reg r (0..7) is z-gate channel c, reg r+8 is f-gate channel c+16.
    int h = h0 + wid;
    int co_hi = 4 * (lane >> 5);
    #pragma unroll
    for (int n = 0; n < 4; ++n) {
        int w = n * 32 + wl;
        #pragma unroll
        for (int r = 0; r < 8; ++r) {
            int c = (r & 3) + 8 * (r >> 2) + co_hi;   // 0..15
            float zv = tanhf_fast(acc[n][r]);
            float fv = sigmoidf_fast(acc[n][r + 8]);
            zf[((size_t)(b * HC + c) * BD + d) * PLANE + h * WW + w] =
                __floats2half2_rn(zv, fv);
        }
    }
}

// ---------------------------------------------------------------------------
// Scan over D. One thread per (b,h,w) column; reads half2(z,f), overwrites
// each consumed 4B slot with fp32 h.
// ---------------------------------------------------------------------------
__global__ __launch_bounds__(256)
void scan_kernel(float* out, const int* __restrict__ rev_p)
{
    int tid = blockIdx.x * 256 + threadIdx.x;
    int b   = tid >> 14;
    int pix = tid & 16383;
    int rev = rev_p[0];

    const unsigned* zfw = (const unsigned*)out;
    size_t cbase = (size_t)b * HC * CH_STRIDE + pix;

    float hreg[16];
    #pragma unroll
    for (int c = 0; c < 16; ++c) hreg[c] = 0.f;

    int d0 = rev ? (BD - 1) : 0;
    unsigned nz[16];
    {
        size_t bs = cbase + (size_t)d0 * PLANE;
        #pragma unroll
        for (int c = 0; c < 16; ++c) nz[c] = zfw[bs + (size_t)c * CH_STRIDE];
    }

    #pragma unroll 1
    for (int dd = 0; dd < BD; ++dd) {
        unsigned cz[16];
        #pragma unroll
        for (int c = 0; c < 16; ++c) cz[c] = nz[c];

        int d = rev ? (BD - 1 - dd) : dd;
        size_t base = cbase + (size_t)d * PLANE;

        if (dd + 1 < BD) {
            int dn = rev ? (BD - 2 - dd) : (dd + 1);
            size_t bn = cbase + (size_t)dn * PLANE;
            #pragma unroll
            for (int c = 0; c < 16; ++c) nz[c] = zfw[bn + (size_t)c * CH_STRIDE];
        }

        #pragma unroll
        for (int c = 0; c < 16; ++c) {
            __half2 v = *(__half2*)&cz[c];
            float z = __low2float(v);
            float f = __high2float(v);
            hreg[c] = f * hreg[c] + (1.f - f) * z;
            out[base + (size_t)c * CH_STRIDE] = hreg[c];
        }
    }
}

// ---------------------------------------------------------------------------
// MLP head, one thread per (b,d,pixel) point, weights in LDS (transposed).
// ---------------------------------------------------------------------------
__global__ __launch_bounds__(256)
void mlp_kernel(float* out,
                const float* __restrict__ w1,
                const float* __restrict__ w2,
                const float* __restrict__ w3)
{
    __shared__ __align__(16) float w1t[32][16];
    __shared__ __align__(16) float w3t[32][16];
    __shared__ __align__(16) float w2t[16][32];

    int t = threadIdx.x;
    for (int i = t; i < 512; i += 256) {
        int j = i >> 4, k = i & 15;
        w1t[j][k] = w1[k * 32 + j];
        w3t[j][k] = w3[k * 32 + j];
    }
    for (int i = t; i < 512; i += 256) {
        int c = i >> 5, j = i & 31;
        w2t[c][j] = w2[j * 16 + c];
    }
    __syncthreads();

    int tid  = blockIdx.x * 256 + t;
    int pix  = tid & 16383;
    int rest = tid >> 14;
    int b    = rest / BD;
    int d    = rest % BD;

    size_t base = (size_t)b * HC * CH_STRIDE + (size_t)d * PLANE + pix;

    float h[16];
    #pragma unroll
    for (int c = 0; c < 16; ++c) h[c] = out[base + (size_t)c * CH_STRIDE];

    float g1[32];
    #pragma unroll
    for (int j = 0; j < 32; ++j) {
        const float4* wp = (const float4*)w1t[j];
        float s = 0.f;
        #pragma unroll
        for (int q = 0; q < 4; ++q) {
            float4 wq = wp[q];
            s += h[q * 4 + 0] * wq.x + h[q * 4 + 1] * wq.y +
                 h[q * 4 + 2] * wq.z + h[q * 4 + 3] * wq.w;
        }
        g1[j] = 0.5f * s * (1.f + erff(s * 0.70710678118f));
    }

    float x1[16];
    #pragma unroll
    for (int c = 0; c < 16; ++c) {
        const float4* wp = (const float4*)w2t[c];
        float s = 0.f;
        #pragma unroll
        for (int q = 0; q < 8; ++q) {
            float4 wq = wp[q];
            s += g1[q * 4 + 0] * wq.x + g1[q * 4 + 1] * wq.y +
                 g1[q * 4 + 2] * wq.z + g1[q * 4 + 3] * wq.w;
        }
        x1[c] = s;
    }

    #pragma unroll
    for (int c = 0; c < 16; ++c) {
        const float4* wa = (const float4*)w3t[c];
        const float4* wb = (const float4*)w3t[c + 16];
        float a = 0.f, wg = 0.f;
        #pragma unroll
        for (int q = 0; q < 4; ++q) {
            float4 qa = wa[q], qb = wb[q];
            a  += h[q * 4 + 0] * qa.x + h[q * 4 + 1] * qa.y +
                  h[q * 4 + 2] * qa.z + h[q * 4 + 3] * qa.w;
            wg += h[q * 4 + 0] * qb.x + h[q * 4 + 1] * qb.y +
                  h[q * 4 + 2] * qb.z + h[q * 4 + 3] * qb.w;
        }
        out[base + (size_t)c * CH_STRIDE] = x1[c] + a * sigmoidf_fast(wg);
    }
}

extern "C" void kernel_launch(void* const* d_in, const int* in_sizes, int n_in,
                              void* d_out, int out_size, void* d_ws, size_t ws_size,
                              hipStream_t stream)
{
    const float* inp = (const float*)d_in[0];
    const float* cw  = (const float*)d_in[1];
    const float* w1  = (const float*)d_in[2];
    const float* w2  = (const float*)d_in[3];
    const float* w3  = (const float*)d_in[4];
    const int*   rev = (const int*)d_in[5];

    ushort* wtab = (ushort*)d_ws;   // 27648 B

    wprep_kernel<<<dim3(54), dim3(256), 0, stream>>>(cw, wtab);

    // 4b * 31d * 32 htiles = 3968 blocks
    conv_gates_mfma<<<dim3(3968), dim3(256), 0, stream>>>(
        inp, wtab, (__half2*)d_out);

    scan_kernel<<<dim3(65536 / 256), dim3(256), 0, stream>>>(
        (float*)d_out, rev);

    mlp_kernel<<<dim3(4 * BD * PLANE / 256), dim3(256), 0, stream>>>(
        (float*)d_out, w1, w2, w3);
}

// Round 4
// 314.277 us; speedup vs baseline: 28.9499x; 1.0924x over previous
//
#include <hip/hip_runtime.h>
#include <hip/hip_fp16.h>

#define HC 16
#define CIN 16
#define BD 31
#define HH 128
#define WW 128
#define PLANE (HH*WW)           // 16384
#define CH_STRIDE (BD*PLANE)    // 507904

typedef __attribute__((ext_vector_type(8))) short bf16x8;   // 8 bf16 = 4 VGPR
typedef __attribute__((ext_vector_type(16))) float f32x16;  // MFMA 32x32 acc

__device__ __forceinline__ float sigmoidf_fast(float x) {
    return 1.0f / (1.0f + __expf(-x));
}
__device__ __forceinline__ float tanhf_fast(float x) {
    return 2.0f / (1.0f + __expf(-2.0f * x)) - 1.0f;
}
__device__ __forceinline__ ushort f2bf(float f) {   // RNE float->bf16
    unsigned u = __float_as_uint(f);
    u = (u + 0x7fffu + ((u >> 16) & 1u)) >> 16;
    return (ushort)u;
}

// ---------------------------------------------------------------------------
// Weight prep (unchanged): per-lane MFMA A-fragments in d_ws.
// wtab[kd][tap][lane][j] (bf16): co = lane&31, ci = 8*(lane>>5)+j.
// ---------------------------------------------------------------------------
__global__ void wprep_kernel(const float* __restrict__ cw, ushort* __restrict__ wtab)
{
    int idx = blockIdx.x * 256 + threadIdx.x;
    if (idx >= 3 * 9 * 64 * 8) return;
    int j    = idx & 7;
    int lane = (idx >> 3) & 63;
    int t    = (idx >> 9) % 9;
    int kd   = (idx >> 9) / 9;
    int co = lane & 31;
    int ci = 8 * (lane >> 5) + j;
    int kh = t / 3, kw = t % 3;
    wtab[idx] = f2bf(cw[(co * CIN + ci) * 27 + kd * 9 + kh * 3 + kw]);
}

// ---------------------------------------------------------------------------
// Slab swizzle (same as round 3): byte = (row*4224 + wcol*32 + cio) ^ ((wcol&0xE)<<3)
// Injective (triangular bit map: b4^=b6, b5^=b7, b6^=b8). Bank-conflict-free
// (measured 0 in round 3).
// ---------------------------------------------------------------------------
#define SLAB_BYTES (6 * 4224)   // 25344 B

__device__ __forceinline__ unsigned slab_byte(int row, int wcol, int cioff) {
    unsigned b = (unsigned)(row * 4224 + wcol * 32 + cioff);
    return b ^ ((unsigned)(wcol & 0xE) << 3);
}

// ---------------------------------------------------------------------------
// xprep: transpose/convert inp fp32 [b][ci][d][h][w] -> bf16 rows
// xT[b][d][h][4096B], ci innermost, with the slab swizzle PRE-BAKED so the
// conv can stage rows with linear global_load_lds (swizzle source, not dest).
// Row byte for (w, q in {0,1}): ((w+1)*32 + q*16) ^ (((w+1)&0xE)<<3) - 32.
// Block: one (b,d) x 2 h-rows (256 pixels). LDS tile transpose, conflict-free.
// ---------------------------------------------------------------------------
__global__ __launch_bounds__(256)
void xprep_kernel(const float* __restrict__ inp, char* __restrict__ xT)
{
    __shared__ float tile[16][256];
    int t  = threadIdx.x;
    int hp = blockIdx.x & 63;
    int g  = blockIdx.x >> 6;
    int d  = g % BD;
    int b  = g / BD;

    size_t src = (size_t)b * CIN * CH_STRIDE + (size_t)d * PLANE + hp * 256;
    #pragma unroll
    for (int c = 0; c < 16; ++c)
        tile[c][t] = inp[src + (size_t)c * CH_STRIDE + t];
    __syncthreads();

    int w  = t & 127;
    int rr = t >> 7;
    char* rowp = xT + (((size_t)(b * BD + d) * 128) + hp * 2 + rr) * 4096;
    #pragma unroll
    for (int q = 0; q < 2; ++q) {
        uint4 pk;
        pk.x = (unsigned)f2bf(tile[q*8+0][t]) | ((unsigned)f2bf(tile[q*8+1][t]) << 16);
        pk.y = (unsigned)f2bf(tile[q*8+2][t]) | ((unsigned)f2bf(tile[q*8+3][t]) << 16);
        pk.z = (unsigned)f2bf(tile[q*8+4][t]) | ((unsigned)f2bf(tile[q*8+5][t]) << 16);
        pk.w = (unsigned)f2bf(tile[q*8+6][t]) | ((unsigned)f2bf(tile[q*8+7][t]) << 16);
        unsigned off = ((unsigned)((w + 1) * 32 + q * 16) ^ (((unsigned)(w + 1) & 0xE) << 3)) - 32;
        *(uint4*)(rowp + off) = pk;
    }
}

// ---------------------------------------------------------------------------
// Conv via MFMA, fast path: slab staged from pre-swizzled xT via
// global_load_lds dwordx4 (6 x 1KB wave-copies per kd). MFMA/epilogue
// identical to the verified round-3 kernel.
// ---------------------------------------------------------------------------
__device__ __forceinline__ void gload_lds16(const void* g, void* l) {
    __builtin_amdgcn_global_load_lds(
        (const __attribute__((address_space(1))) unsigned int*)g,
        (__attribute__((address_space(3))) unsigned int*)l, 16, 0, 0);
}

__global__ __launch_bounds__(256, 3)
void conv_gates_mfma_fast(const char* __restrict__ xT,
                          const ushort* __restrict__ wtab,
                          __half2* __restrict__ zf)
{
    __shared__ __align__(16) char slab[SLAB_BYTES];

    int p = blockIdx.x;
    int logical = (p & 7) * 496 + (p >> 3);   // XCD-aware: same (b,d) on one XCD
    int ht = logical & 31;
    int g  = logical >> 5;
    int d  = g % BD;
    int b  = g / BD;
    int h0 = ht * 4;

    int lane = threadIdx.x & 63;
    int wid  = threadIdx.x >> 6;
    int wl   = lane & 31;
    int cio  = (lane >> 5) * 16;

    // zero the edge regions once: per row, bytes [0,32) (wcol 0) and
    // [4128,4224) (wcol 129..131). Loads never touch them; reads at
    // wcol 0/129 then see zeros. Visible after first __syncthreads.
    if (threadIdx.x < 192) {
        int r = threadIdx.x >> 5;
        int k = threadIdx.x & 31;
        int off = (k < 8) ? (k * 4) : (4128 + (k - 8) * 4);
        *(int*)(slab + r * 4224 + off) = 0;
    }

    f32x16 acc[4];
    #pragma unroll
    for (int n = 0; n < 4; ++n)
        #pragma unroll
        for (int r = 0; r < 16; ++r) acc[n][r] = 0.f;

    const bf16x8* wt = (const bf16x8*)wtab;

    #pragma unroll 1
    for (int kd = 0; kd < 3; ++kd) {
        int dd = d + kd - 1;
        if (dd < 0 || dd >= BD) continue;   // uniform per block

        __syncthreads();   // previous slab fully consumed (+ zeroing visible)
        const char* plane = xT + ((size_t)(b * BD + dd) * 128) * 4096;
        // 24 x 1KB copies (6 rows x 4 chunks); wave-uniform rows.
        for (int i = wid; i < 24; i += 4) {
            int r  = i >> 2;
            int ch = i & 3;
            int h  = h0 - 1 + r;
            char* dst = slab + r * 4224 + 32 + ch * 1024;
            if ((unsigned)h < HH) {
                const char* s = plane + (size_t)h * 4096 + ch * 1024 + lane * 16;
                gload_lds16(s, dst);
            } else {
                *(uint4*)(dst + lane * 16) = uint4{0, 0, 0, 0};
            }
        }
        __syncthreads();   // drains vmcnt -> slab ready

        bf16x8 af[9];
        #pragma unroll
        for (int t = 0; t < 9; ++t)
            af[t] = wt[(kd * 9 + t) * 64 + lane];

        #pragma unroll
        for (int t = 0; t < 9; ++t) {
            int dh = t / 3 - 1;
            int dw = t % 3 - 1;
            int row = wid + 1 + dh;
            #pragma unroll
            for (int n = 0; n < 4; ++n) {
                int wcol = n * 32 + wl + 1 + dw;
                bf16x8 bfr = *(const bf16x8*)(slab + slab_byte(row, wcol, cio));
                acc[n] = __builtin_amdgcn_mfma_f32_32x32x16_bf16(af[t], bfr, acc[n], 0, 0, 0);
            }
        }
    }

    // epilogue: C/D map col=lane&31, row=(reg&3)+8*(reg>>2)+4*(lane>>5)
    int h = h0 + wid;
    int co_hi = 4 * (lane >> 5);
    #pragma unroll
    for (int n = 0; n < 4; ++n) {
        int w = n * 32 + wl;
        #pragma unroll
        for (int r = 0; r < 8; ++r) {
            int c = (r & 3) + 8 * (r >> 2) + co_hi;
            float zv = tanhf_fast(acc[n][r]);
            float fv = sigmoidf_fast(acc[n][r + 8]);
            zf[((size_t)(b * HC + c) * BD + d) * PLANE + h * WW + w] =
                __floats2half2_rn(zv, fv);
        }
    }
}

// ---------------------------------------------------------------------------
// Conv fallback (round-3 verified path, reg staging from fp32) — used only
// if ws_size can't hold the 65MB bf16 buffer.
// ---------------------------------------------------------------------------
__global__ __launch_bounds__(256, 3)
void conv_gates_mfma(const float* __restrict__ inp,
                     const ushort* __restrict__ wtab,
                     __half2* __restrict__ zf)
{
    __shared__ __align__(16) char slab[SLAB_BYTES];

    int p = blockIdx.x;
    int logical = (p & 7) * 496 + (p >> 3);
    int ht = logical & 31;
    int g  = logical >> 5;
    int d  = g % BD;
    int b  = g / BD;
    int h0 = ht * 4;

    int lane = threadIdx.x & 63;
    int wid  = threadIdx.x >> 6;
    int wl   = lane & 31;
    int cio  = (lane >> 5) * 16;

    f32x16 acc[4];
    #pragma unroll
    for (int n = 0; n < 4; ++n)
        #pragma unroll
        for (int r = 0; r < 16; ++r) acc[n][r] = 0.f;

    const bf16x8* wt = (const bf16x8*)wtab;

    #pragma unroll 1
    for (int kd = 0; kd < 3; ++kd) {
        int dd = d + kd - 1;
        if (dd < 0 || dd >= BD) continue;

        __syncthreads();
        #pragma unroll 1
        for (int it = threadIdx.x; it < 6 * 132 * 4; it += 256) {
            int q    = it & 3;
            int rest = it >> 2;
            int wcol = rest % 132;
            int row  = rest / 132;
            int h = h0 + row - 1;
            int w = wcol - 1;
            float v0 = 0.f, v1 = 0.f, v2 = 0.f, v3 = 0.f;
            if ((unsigned)h < HH && (unsigned)w < WW) {
                const float* pin = inp
                    + ((size_t)(b * CIN + q * 4) * BD + dd) * PLANE + h * WW + w;
                v0 = pin[0];
                v1 = pin[CH_STRIDE];
                v2 = pin[2 * CH_STRIDE];
                v3 = pin[3 * CH_STRIDE];
            }
            uint2 pk;
            pk.x = (unsigned)f2bf(v0) | ((unsigned)f2bf(v1) << 16);
            pk.y = (unsigned)f2bf(v2) | ((unsigned)f2bf(v3) << 16);
            *(uint2*)(slab + slab_byte(row, wcol, q * 8)) = pk;
        }
        __syncthreads();

        bf16x8 af[9];
        #pragma unroll
        for (int t = 0; t < 9; ++t)
            af[t] = wt[(kd * 9 + t) * 64 + lane];

        #pragma unroll
        for (int t = 0; t < 9; ++t) {
            int dh = t / 3 - 1;
            int dw = t % 3 - 1;
            int row = wid + 1 + dh;
            #pragma unroll
            for (int n = 0; n < 4; ++n) {
                int wcol = n * 32 + wl + 1 + dw;
                bf16x8 bfr = *(const bf16x8*)(slab + slab_byte(row, wcol, cio));
                acc[n] = __builtin_amdgcn_mfma_f32_32x32x16_bf16(af[t], bfr, acc[n], 0, 0, 0);
            }
        }
    }

    int h = h0 + wid;
    int co_hi = 4 * (lane >> 5);
    #pragma unroll
    for (int n = 0; n < 4; ++n) {
        int w = n * 32 + wl;
        #pragma unroll
        for (int r = 0; r < 8; ++r) {
            int c = (r & 3) + 8 * (r >> 2) + co_hi;
            float zv = tanhf_fast(acc[n][r]);
            float fv = sigmoidf_fast(acc[n][r + 8]);
            zf[((size_t)(b * HC + c) * BD + d) * PLANE + h * WW + w] =
                __floats2half2_rn(zv, fv);
        }
    }
}

// ---------------------------------------------------------------------------
// Scan over D, one thread per (b,pix,channel): recurrence is per-channel
// independent -> 1M threads (vs 64K) for latency hiding. Reads half2(z,f),
// overwrites the consumed 4B slot with fp32 h.
// ---------------------------------------------------------------------------
__global__ __launch_bounds__(256)
void scan_kernel(float* out, const int* __restrict__ rev_p)
{
    int tid = blockIdx.x * 256 + threadIdx.x;   // 4*16*16384 = 1,048,576
    int pix = tid & 16383;
    int c   = (tid >> 14) & 15;
    int b   = tid >> 18;
    int rev = rev_p[0];

    const unsigned* zfw = (const unsigned*)out;
    long long cur = (long long)(b * HC + c) * CH_STRIDE + pix
                  + (rev ? (long long)(BD - 1) * PLANE : 0);
    long long dstep = rev ? -(long long)PLANE : (long long)PLANE;

    float h = 0.f;
    unsigned nz = zfw[cur];
    #pragma unroll 1
    for (int dd = 0; dd < BD; ++dd) {
        unsigned cz = nz;
        long long at = cur;
        cur += dstep;
        if (dd + 1 < BD) nz = zfw[cur];

        __half2 v = *(__half2*)&cz;
        float z = __low2float(v);
        float f = __high2float(v);
        h = f * h + (1.f - f) * z;
        out[at] = h;
    }
}

// ---------------------------------------------------------------------------
// MLP head (unchanged): one thread per (b,d,pixel), weights in LDS.
// ---------------------------------------------------------------------------
__global__ __launch_bounds__(256)
void mlp_kernel(float* out,
                const float* __restrict__ w1,
                const float* __restrict__ w2,
                const float* __restrict__ w3)
{
    __shared__ __align__(16) float w1t[32][16];
    __shared__ __align__(16) float w3t[32][16];
    __shared__ __align__(16) float w2t[16][32];

    int t = threadIdx.x;
    for (int i = t; i < 512; i += 256) {
        int j = i >> 4, k = i & 15;
        w1t[j][k] = w1[k * 32 + j];
        w3t[j][k] = w3[k * 32 + j];
    }
    for (int i = t; i < 512; i += 256) {
        int c = i >> 5, j = i & 31;
        w2t[c][j] = w2[j * 16 + c];
    }
    __syncthreads();

    int tid  = blockIdx.x * 256 + t;
    int pix  = tid & 16383;
    int rest = tid >> 14;
    int b    = rest / BD;
    int d    = rest % BD;

    size_t base = (size_t)b * HC * CH_STRIDE + (size_t)d * PLANE + pix;

    float h[16];
    #pragma unroll
    for (int c = 0; c < 16; ++c) h[c] = out[base + (size_t)c * CH_STRIDE];

    float g1[32];
    #pragma unroll
    for (int j = 0; j < 32; ++j) {
        const float4* wp = (const float4*)w1t[j];
        float s = 0.f;
        #pragma unroll
        for (int q = 0; q < 4; ++q) {
            float4 wq = wp[q];
            s += h[q * 4 + 0] * wq.x + h[q * 4 + 1] * wq.y +
                 h[q * 4 + 2] * wq.z + h[q * 4 + 3] * wq.w;
        }
        g1[j] = 0.5f * s * (1.f + erff(s * 0.70710678118f));
    }

    float x1[16];
    #pragma unroll
    for (int c = 0; c < 16; ++c) {
        const float4* wp = (const float4*)w2t[c];
        float s = 0.f;
        #pragma unroll
        for (int q = 0; q < 8; ++q) {
            float4 wq = wp[q];
            s += g1[q * 4 + 0] * wq.x + g1[q * 4 + 1] * wq.y +
                 g1[q * 4 + 2] * wq.z + g1[q * 4 + 3] * wq.w;
        }
        x1[c] = s;
    }

    #pragma unroll
    for (int c = 0; c < 16; ++c) {
        const float4* wa = (const float4*)w3t[c];
        const float4* wb = (const float4*)w3t[c + 16];
        float a = 0.f, wg = 0.f;
        #pragma unroll
        for (int q = 0; q < 4; ++q) {
            float4 qa = wa[q], qb = wb[q];
            a  += h[q * 4 + 0] * qa.x + h[q * 4 + 1] * qa.y +
                  h[q * 4 + 2] * qa.z + h[q * 4 + 3] * qa.w;
            wg += h[q * 4 + 0] * qb.x + h[q * 4 + 1] * qb.y +
                  h[q * 4 + 2] * qb.z + h[q * 4 + 3] * qb.w;
        }
        out[base + (size_t)c * CH_STRIDE] = x1[c] + a * sigmoidf_fast(wg);
    }
}

extern "C" void kernel_launch(void* const* d_in, const int* in_sizes, int n_in,
                              void* d_out, int out_size, void* d_ws, size_t ws_size,
                              hipStream_t stream)
{
    const float* inp = (const float*)d_in[0];
    const float* cw  = (const float*)d_in[1];
    const float* w1  = (const float*)d_in[2];
    const float* w2  = (const float*)d_in[3];
    const float* w3  = (const float*)d_in[4];
    const int*   rev = (const int*)d_in[5];

    ushort* wtab = (ushort*)d_ws;                  // 27648 B
    char*   xT   = (char*)d_ws + 32768;            // 65,011,712 B
    const size_t need = 32768 + (size_t)4 * BD * 128 * 4096;

    wprep_kernel<<<dim3(54), dim3(256), 0, stream>>>(cw, wtab);

    if (ws_size >= need) {
        // transpose/convert: 4b * 31d * 64 h-pairs = 7936 blocks
        xprep_kernel<<<dim3(7936), dim3(256), 0, stream>>>(inp, xT);
        conv_gates_mfma_fast<<<dim3(3968), dim3(256), 0, stream>>>(
            xT, wtab, (__half2*)d_out);
    } else {
        conv_gates_mfma<<<dim3(3968), dim3(256), 0, stream>>>(
            inp, wtab, (__half2*)d_out);
    }

    scan_kernel<<<dim3(4096), dim3(256), 0, stream>>>((float*)d_out, rev);

    mlp_kernel<<<dim3(4 * BD * PLANE / 256), dim3(256), 0, stream>>>(
        (float*)d_out, w1, w2, w3);
}

// Round 5
// 214.050 us; speedup vs baseline: 42.5053x; 1.4682x over previous
//
#include <hip/hip_runtime.h>
#include <hip/hip_fp16.h>

#define HC 16
#define CIN 16
#define BD 31
#define HH 128
#define WW 128
#define PLANE (HH*WW)           // 16384
#define CH_STRIDE (BD*PLANE)    // 507904

typedef __attribute__((ext_vector_type(8))) short bf16x8;   // 8 bf16 = 4 VGPR
typedef __attribute__((ext_vector_type(16))) float f32x16;  // MFMA 32x32 acc

__device__ __forceinline__ float sigmoidf_fast(float x) {
    return 1.0f / (1.0f + __expf(-x));
}
__device__ __forceinline__ float tanhf_fast(float x) {
    return 2.0f / (1.0f + __expf(-2.0f * x)) - 1.0f;
}
__device__ __forceinline__ ushort f2bf(float f) {   // RNE float->bf16
    unsigned u = __float_as_uint(f);
    u = (u + 0x7fffu + ((u >> 16) & 1u)) >> 16;
    return (ushort)u;
}
// exact-gelu via Abramowitz-Stegun 7.1.26 erf (|eps|<=1.5e-7)
__device__ __forceinline__ float gelu_as(float s) {
    float z  = 0.70710678118f * s;
    float az = fabsf(z);
    float t  = __builtin_amdgcn_rcpf(fmaf(0.3275911f, az, 1.0f));
    float p  = t * (0.254829592f + t * (-0.284496736f + t * (1.421413741f
             + t * (-1.453152027f + t * 1.061405429f))));
    float e  = __expf(-z * z);
    float er = copysignf(1.0f - p * e, z);
    return 0.5f * s * (1.0f + er);
}

// ---------------------------------------------------------------------------
// Conv weight prep: wtab[kd][tap][lane][j] (bf16): co=lane&31, ci=8*(lane>>5)+j.
// ---------------------------------------------------------------------------
__global__ void wprep_kernel(const float* __restrict__ cw, ushort* __restrict__ wtab)
{
    int idx = blockIdx.x * 256 + threadIdx.x;
    if (idx >= 3 * 9 * 64 * 8) return;
    int j    = idx & 7;
    int lane = (idx >> 3) & 63;
    int t    = (idx >> 9) % 9;
    int kd   = (idx >> 9) / 9;
    int co = lane & 31;
    int ci = 8 * (lane >> 5) + j;
    int kh = t / 3, kw = t % 3;
    wtab[idx] = f2bf(cw[(co * CIN + ci) * 27 + kd * 9 + kh * 3 + kw]);
}

// ---------------------------------------------------------------------------
// MLP weight prep: 4 fragment tables x 64 lanes x 8 bf16 (4KB total).
// tbl0: w1^T A-frag  (m=j=lane&31,  k=ci=8*hi+e)
// tbl1/2: w2 A-frags mf=0/1 with permuted k: j=(e&3)+8*(e>>2)+4*hi+16*mf
//         (rows m>=16 zero-padded)
// tbl3: w3^T A-frag  (m=lane&31 in 0..31 = [a|wg] rows, k=ci=8*hi+e)
// The same k-permutation is applied to the B side in the MLP kernel, so the
// result is invariant to the HW k-slot ordering (shared-k-permutation).
// ---------------------------------------------------------------------------
__global__ void wprep2_kernel(const float* __restrict__ w1,
                              const float* __restrict__ w2,
                              const float* __restrict__ w3,
                              ushort* __restrict__ wtab2)
{
    int idx = blockIdx.x * 256 + threadIdx.x;
    if (idx >= 2048) return;
    int e    = idx & 7;
    int lane = (idx >> 3) & 63;
    int tbl  = idx >> 9;
    int m  = lane & 31;
    int hi = lane >> 5;
    float v = 0.f;
    if (tbl == 0)      v = w1[(8 * hi + e) * 32 + m];
    else if (tbl == 3) v = w3[(8 * hi + e) * 32 + m];
    else {
        int mf = tbl - 1;
        if (m < 16) v = w2[((e & 3) + 8 * (e >> 2) + 4 * hi + 16 * mf) * 16 + m];
    }
    wtab2[idx] = f2bf(v);
}

// ---------------------------------------------------------------------------
// Slab swizzle: byte = (row*4224 + wcol*32 + cio) ^ ((wcol&0xE)<<3). Injective,
// bank-conflict-free (measured 0).
// ---------------------------------------------------------------------------
#define SLAB_BYTES (6 * 4224)   // 25344 B

__device__ __forceinline__ unsigned slab_byte(int row, int wcol, int cioff) {
    unsigned b = (unsigned)(row * 4224 + wcol * 32 + cioff);
    return b ^ ((unsigned)(wcol & 0xE) << 3);
}

// ---------------------------------------------------------------------------
// xprep: fp32 [b][ci][d][h][w] -> bf16 rows xT[b][d][h][4096B], ci innermost,
// slab swizzle pre-baked (swizzle-source + linear gload_lds dest, rule #21).
// ---------------------------------------------------------------------------
__global__ __launch_bounds__(256)
void xprep_kernel(const float* __restrict__ inp, char* __restrict__ xT)
{
    __shared__ float tile[16][256];
    int t  = threadIdx.x;
    int hp = blockIdx.x & 63;
    int g  = blockIdx.x >> 6;
    int d  = g % BD;
    int b  = g / BD;

    size_t src = (size_t)b * CIN * CH_STRIDE + (size_t)d * PLANE + hp * 256;
    #pragma unroll
    for (int c = 0; c < 16; ++c)
        tile[c][t] = inp[src + (size_t)c * CH_STRIDE + t];
    __syncthreads();

    int w  = t & 127;
    int rr = t >> 7;
    char* rowp = xT + (((size_t)(b * BD + d) * 128) + hp * 2 + rr) * 4096;
    #pragma unroll
    for (int q = 0; q < 2; ++q) {
        uint4 pk;
        pk.x = (unsigned)f2bf(tile[q*8+0][t]) | ((unsigned)f2bf(tile[q*8+1][t]) << 16);
        pk.y = (unsigned)f2bf(tile[q*8+2][t]) | ((unsigned)f2bf(tile[q*8+3][t]) << 16);
        pk.z = (unsigned)f2bf(tile[q*8+4][t]) | ((unsigned)f2bf(tile[q*8+5][t]) << 16);
        pk.w = (unsigned)f2bf(tile[q*8+6][t]) | ((unsigned)f2bf(tile[q*8+7][t]) << 16);
        unsigned off = ((unsigned)((w + 1) * 32 + q * 16) ^ (((unsigned)(w + 1) & 0xE) << 3)) - 32;
        *(uint4*)(rowp + off) = pk;
    }
}

// ---------------------------------------------------------------------------
// Conv via MFMA (gload_lds staging from pre-swizzled xT). NEW epilogue layout:
// zf[bd][pt][c] half2, point-major, for coalesced scan/MLP consumption.
// ---------------------------------------------------------------------------
__device__ __forceinline__ void gload_lds16(const void* g, void* l) {
    __builtin_amdgcn_global_load_lds(
        (const __attribute__((address_space(1))) unsigned int*)g,
        (__attribute__((address_space(3))) unsigned int*)l, 16, 0, 0);
}

__global__ __launch_bounds__(256, 3)
void conv_gates_mfma_fast(const char* __restrict__ xT,
                          const ushort* __restrict__ wtab,
                          __half2* __restrict__ zf)
{
    __shared__ __align__(16) char slab[SLAB_BYTES];

    int p = blockIdx.x;
    int logical = (p & 7) * 496 + (p >> 3);   // XCD-aware
    int ht = logical & 31;
    int g  = logical >> 5;
    int d  = g % BD;
    int b  = g / BD;
    int h0 = ht * 4;

    int lane = threadIdx.x & 63;
    int wid  = threadIdx.x >> 6;
    int wl   = lane & 31;
    int cio  = (lane >> 5) * 16;

    if (threadIdx.x < 192) {
        int r = threadIdx.x >> 5;
        int k = threadIdx.x & 31;
        int off = (k < 8) ? (k * 4) : (4128 + (k - 8) * 4);
        *(int*)(slab + r * 4224 + off) = 0;
    }

    f32x16 acc[4];
    #pragma unroll
    for (int n = 0; n < 4; ++n)
        #pragma unroll
        for (int r = 0; r < 16; ++r) acc[n][r] = 0.f;

    const bf16x8* wt = (const bf16x8*)wtab;

    #pragma unroll 1
    for (int kd = 0; kd < 3; ++kd) {
        int dd = d + kd - 1;
        if (dd < 0 || dd >= BD) continue;

        __syncthreads();
        const char* plane = xT + ((size_t)(b * BD + dd) * 128) * 4096;
        for (int i = wid; i < 24; i += 4) {
            int r  = i >> 2;
            int ch = i & 3;
            int h  = h0 - 1 + r;
            char* dst = slab + r * 4224 + 32 + ch * 1024;
            if ((unsigned)h < HH) {
                const char* s = plane + (size_t)h * 4096 + ch * 1024 + lane * 16;
                gload_lds16(s, dst);
            } else {
                *(uint4*)(dst + lane * 16) = uint4{0, 0, 0, 0};
            }
        }
        __syncthreads();

        bf16x8 af[9];
        #pragma unroll
        for (int t = 0; t < 9; ++t)
            af[t] = wt[(kd * 9 + t) * 64 + lane];

        #pragma unroll
        for (int t = 0; t < 9; ++t) {
            int dh = t / 3 - 1;
            int dw = t % 3 - 1;
            int row = wid + 1 + dh;
            #pragma unroll
            for (int n = 0; n < 4; ++n) {
                int wcol = n * 32 + wl + 1 + dw;
                bf16x8 bfr = *(const bf16x8*)(slab + slab_byte(row, wcol, cio));
                acc[n] = __builtin_amdgcn_mfma_f32_32x32x16_bf16(af[t], bfr, acc[n], 0, 0, 0);
            }
        }
    }

    // epilogue: point-major zf. C/D map col=lane&31, row=(r&3)+8*(r>>2)+4*(lane>>5)
    int h = h0 + wid;
    int co_hi = 4 * (lane >> 5);
    size_t tbase = ((size_t)(b * BD + d) * PLANE + (size_t)h * WW);
    #pragma unroll
    for (int n = 0; n < 4; ++n) {
        int w = n * 32 + wl;
        size_t pb = (tbase + w) * 16;
        #pragma unroll
        for (int r = 0; r < 8; ++r) {
            int c = (r & 3) + 8 * (r >> 2) + co_hi;
            float zv = tanhf_fast(acc[n][r]);
            float fv = sigmoidf_fast(acc[n][r + 8]);
            zf[pb + c] = __floats2half2_rn(zv, fv);
        }
    }
}

// ---------------------------------------------------------------------------
// Scan over D. Thread = (b, pt, c): reads zf[bd][pt][c] half2 (256B/wave
// coalesced), writes bf16 h into hbuf[bd][pt][c] (128B/wave coalesced).
// ---------------------------------------------------------------------------
__global__ __launch_bounds__(256)
void scan_kernel(const __half2* __restrict__ zf, ushort* __restrict__ hbuf,
                 const int* __restrict__ rev_p)
{
    int tid = blockIdx.x * 256 + threadIdx.x;   // 4*16384*16 = 1,048,576
    int c   = tid & 15;
    int pt  = (tid >> 4) & 16383;
    int b   = tid >> 18;
    int rev = rev_p[0];

    const unsigned* zfw = (const unsigned*)zf;
    size_t col = ((size_t)b * BD) * PLANE * 16 + (size_t)pt * 16 + c;
    long long cur = (long long)col + (rev ? (long long)(BD - 1) * PLANE * 16 : 0);
    long long dstep = rev ? -(long long)PLANE * 16 : (long long)PLANE * 16;

    float h = 0.f;
    unsigned nz = zfw[cur];
    #pragma unroll 1
    for (int dd = 0; dd < BD; ++dd) {
        unsigned cz = nz;
        long long at = cur;
        cur += dstep;
        if (dd + 1 < BD) nz = zfw[cur];

        __half2 v = *(__half2*)&cz;
        float z = __low2float(v);
        float f = __high2float(v);
        h = f * h + (1.f - f) * z;
        hbuf[at] = f2bf(h);
    }
}

// ---------------------------------------------------------------------------
// MLP via MFMA. Wave = 32 points. B-frag = one contiguous 16B hbuf load.
// GEMM1 (w1^T) and GEMM3 (w3^T: rows 0..15 = a, 16..31 = wg) share the B-frag.
// GEMM2 uses the permuted-k trick: post-gelu C/D regs [0..7]/[8..15] packed to
// bf16 ARE the B-frags (no cross-lane movement).
// ---------------------------------------------------------------------------
__global__ __launch_bounds__(256)
void mlp_mfma_kernel(const char* __restrict__ hbuf,
                     const ushort* __restrict__ wtab2,
                     float* __restrict__ out)
{
    int lane = threadIdx.x & 63;
    int wid  = threadIdx.x >> 6;
    int p    = lane & 31;
    int hi   = lane >> 5;

    size_t tile = (size_t)blockIdx.x * 4 + wid;   // 63488 tiles of 32 points
    size_t ptg  = tile * 32 + p;

    const bf16x8* W = (const bf16x8*)wtab2;
    bf16x8 af1  = W[lane];
    bf16x8 af2a = W[64 + lane];
    bf16x8 af2b = W[128 + lane];
    bf16x8 af3  = W[192 + lane];
    bf16x8 bx   = *(const bf16x8*)(hbuf + ptg * 32 + hi * 16);

    f32x16 zacc;
    #pragma unroll
    for (int r = 0; r < 16; ++r) zacc[r] = 0.f;

    f32x16 acc1 = __builtin_amdgcn_mfma_f32_32x32x16_bf16(af1, bx, zacc, 0, 0, 0);
    f32x16 acc3 = __builtin_amdgcn_mfma_f32_32x32x16_bf16(af3, bx, zacc, 0, 0, 0);

    // gelu + pack: reg r holds j=(r&3)+8*(r>>2)+4*hi (+16 for r>=8) — exactly
    // the permuted-k order baked into tbl1/tbl2 A-frags.
    union { bf16x8 v; unsigned u[4]; } b2a, b2b;
    #pragma unroll
    for (int q = 0; q < 4; ++q) {
        float g0 = gelu_as(acc1[2 * q]);
        float g1 = gelu_as(acc1[2 * q + 1]);
        float g8 = gelu_as(acc1[8 + 2 * q]);
        float g9 = gelu_as(acc1[8 + 2 * q + 1]);
        b2a.u[q] = (unsigned)f2bf(g0) | ((unsigned)f2bf(g1) << 16);
        b2b.u[q] = (unsigned)f2bf(g8) | ((unsigned)f2bf(g9) << 16);
    }

    f32x16 acc2 = __builtin_amdgcn_mfma_f32_32x32x16_bf16(af2a, b2a.v, zacc, 0, 0, 0);
    acc2 = __builtin_amdgcn_mfma_f32_32x32x16_bf16(af2b, b2b.v, acc2, 0, 0, 0);

    int bd  = (int)(ptg >> 14);
    int pix = (int)(ptg & 16383);
    int b   = bd / BD;
    int d   = bd % BD;
    float* obase = out + (size_t)b * HC * CH_STRIDE + (size_t)d * PLANE + pix;

    #pragma unroll
    for (int r = 0; r < 8; ++r) {
        int c = (r & 3) + 8 * (r >> 2) + 4 * hi;
        float y = acc2[r] + acc3[r] * sigmoidf_fast(acc3[r + 8]);
        obase[(size_t)c * CH_STRIDE] = y;
    }
}

extern "C" void kernel_launch(void* const* d_in, const int* in_sizes, int n_in,
                              void* d_out, int out_size, void* d_ws, size_t ws_size,
                              hipStream_t stream)
{
    const float* inp = (const float*)d_in[0];
    const float* cw  = (const float*)d_in[1];
    const float* w1  = (const float*)d_in[2];
    const float* w2  = (const float*)d_in[3];
    const float* w3  = (const float*)d_in[4];
    const int*   rev = (const int*)d_in[5];

    ushort* wtab  = (ushort*)d_ws;                    // [0, 27648)
    ushort* wtab2 = (ushort*)((char*)d_ws + 27648);   // [27648, 31744)
    char*   xT    = (char*)d_ws + 32768;              // 65 MB (xprep/conv)
    ushort* hbuf  = (ushort*)xT;                      // reused after conv

    wprep_kernel<<<dim3(54), dim3(256), 0, stream>>>(cw, wtab);
    wprep2_kernel<<<dim3(8), dim3(256), 0, stream>>>(w1, w2, w3, wtab2);

    xprep_kernel<<<dim3(7936), dim3(256), 0, stream>>>(inp, xT);

    conv_gates_mfma_fast<<<dim3(3968), dim3(256), 0, stream>>>(
        xT, wtab, (__half2*)d_out);

    scan_kernel<<<dim3(4096), dim3(256), 0, stream>>>(
        (const __half2*)d_out, hbuf, rev);

    // 2,031,616 points / (4 waves * 32 points) = 15872 blocks
    mlp_mfma_kernel<<<dim3(15872), dim3(256), 0, stream>>>(
        (const char*)hbuf, wtab2, (float*)d_out);
}

// Round 6
// 213.413 us; speedup vs baseline: 42.6322x; 1.0030x over previous
//
#include <hip/hip_runtime.h>
#include <hip/hip_fp16.h>

#define HC 16
#define CIN 16
#define BD 31
#define HH 128
#define WW 128
#define PLANE (HH*WW)           // 16384
#define CH_STRIDE (BD*PLANE)    // 507904

typedef __attribute__((ext_vector_type(8))) short bf16x8;   // 8 bf16 = 4 VGPR
typedef __attribute__((ext_vector_type(16))) float f32x16;  // MFMA 32x32 acc

__device__ __forceinline__ float sigmoidf_fast(float x) {
    return 1.0f / (1.0f + __expf(-x));
}
__device__ __forceinline__ float tanhf_fast(float x) {
    return 2.0f / (1.0f + __expf(-2.0f * x)) - 1.0f;
}
__device__ __forceinline__ ushort f2bf(float f) {   // RNE float->bf16
    unsigned u = __float_as_uint(f);
    u = (u + 0x7fffu + ((u >> 16) & 1u)) >> 16;
    return (ushort)u;
}
// exact-gelu via Abramowitz-Stegun 7.1.26 erf (|eps|<=1.5e-7)
__device__ __forceinline__ float gelu_as(float s) {
    float z  = 0.70710678118f * s;
    float az = fabsf(z);
    float t  = __builtin_amdgcn_rcpf(fmaf(0.3275911f, az, 1.0f));
    float p  = t * (0.254829592f + t * (-0.284496736f + t * (1.421413741f
             + t * (-1.453152027f + t * 1.061405429f))));
    float e  = __expf(-z * z);
    float er = copysignf(1.0f - p * e, z);
    return 0.5f * s * (1.0f + er);
}

// ---------------------------------------------------------------------------
// Conv weight prep: wtab[kd][tap][lane][j] (bf16): co=lane&31, ci=8*(lane>>5)+j.
// ---------------------------------------------------------------------------
__global__ void wprep_kernel(const float* __restrict__ cw, ushort* __restrict__ wtab)
{
    int idx = blockIdx.x * 256 + threadIdx.x;
    if (idx >= 3 * 9 * 64 * 8) return;
    int j    = idx & 7;
    int lane = (idx >> 3) & 63;
    int t    = (idx >> 9) % 9;
    int kd   = (idx >> 9) / 9;
    int co = lane & 31;
    int ci = 8 * (lane >> 5) + j;
    int kh = t / 3, kw = t % 3;
    wtab[idx] = f2bf(cw[(co * CIN + ci) * 27 + kd * 9 + kh * 3 + kw]);
}

// ---------------------------------------------------------------------------
// MLP weight prep (unchanged): 4 fragment tables x 64 lanes x 8 bf16.
// ---------------------------------------------------------------------------
__global__ void wprep2_kernel(const float* __restrict__ w1,
                              const float* __restrict__ w2,
                              const float* __restrict__ w3,
                              ushort* __restrict__ wtab2)
{
    int idx = blockIdx.x * 256 + threadIdx.x;
    if (idx >= 2048) return;
    int e    = idx & 7;
    int lane = (idx >> 3) & 63;
    int tbl  = idx >> 9;
    int m  = lane & 31;
    int hi = lane >> 5;
    float v = 0.f;
    if (tbl == 0)      v = w1[(8 * hi + e) * 32 + m];
    else if (tbl == 3) v = w3[(8 * hi + e) * 32 + m];
    else {
        int mf = tbl - 1;
        if (m < 16) v = w2[((e & 3) + 8 * (e >> 2) + 4 * hi + 16 * mf) * 16 + m];
    }
    wtab2[idx] = f2bf(v);
}

// ---------------------------------------------------------------------------
// Slab swizzle: byte = (row*4224 + wcol*32 + cio) ^ ((wcol&0xE)<<3). Injective,
// bank-conflict-free (measured 0). Decomposition used by the conv inner loop:
// row*4224 + n*1024 has bits 0-6 == 0 and the XOR mask only touches bits 4-6
// of the per-lane part => (X+B)^C == X + (B^C): per-lane base + imm offset.
// ---------------------------------------------------------------------------
#define SLAB_BYTES (6 * 4224)   // 25344 B

__device__ __forceinline__ unsigned slab_byte(int row, int wcol, int cioff) {
    unsigned b = (unsigned)(row * 4224 + wcol * 32 + cioff);
    return b ^ ((unsigned)(wcol & 0xE) << 3);
}

// ---------------------------------------------------------------------------
// xprep: fp32 [b][ci][d][h][w] -> bf16 rows xT[b][d][h][4096B], ci innermost,
// slab swizzle pre-baked (swizzle-source + linear gload_lds dest, rule #21).
// ---------------------------------------------------------------------------
__global__ __launch_bounds__(256)
void xprep_kernel(const float* __restrict__ inp, char* __restrict__ xT)
{
    __shared__ float tile[16][256];
    int t  = threadIdx.x;
    int hp = blockIdx.x & 63;
    int g  = blockIdx.x >> 6;
    int d  = g % BD;
    int b  = g / BD;

    size_t src = (size_t)b * CIN * CH_STRIDE + (size_t)d * PLANE + hp * 256;
    #pragma unroll
    for (int c = 0; c < 16; ++c)
        tile[c][t] = inp[src + (size_t)c * CH_STRIDE + t];
    __syncthreads();

    int w  = t & 127;
    int rr = t >> 7;
    char* rowp = xT + (((size_t)(b * BD + d) * 128) + hp * 2 + rr) * 4096;
    #pragma unroll
    for (int q = 0; q < 2; ++q) {
        uint4 pk;
        pk.x = (unsigned)f2bf(tile[q*8+0][t]) | ((unsigned)f2bf(tile[q*8+1][t]) << 16);
        pk.y = (unsigned)f2bf(tile[q*8+2][t]) | ((unsigned)f2bf(tile[q*8+3][t]) << 16);
        pk.z = (unsigned)f2bf(tile[q*8+4][t]) | ((unsigned)f2bf(tile[q*8+5][t]) << 16);
        pk.w = (unsigned)f2bf(tile[q*8+6][t]) | ((unsigned)f2bf(tile[q*8+7][t]) << 16);
        unsigned off = ((unsigned)((w + 1) * 32 + q * 16) ^ (((unsigned)(w + 1) & 0xE) << 3)) - 32;
        *(uint4*)(rowp + off) = pk;
    }
}

// ---------------------------------------------------------------------------
// Conv via MFMA (gload_lds staging from pre-swizzled xT). Inner loop uses
// 3 per-lane base pointers + compile-time ds_read offsets (zero addr VALU).
// Epilogue: point-major zf, packed 16B stores (c-groups are contiguous).
// ---------------------------------------------------------------------------
__device__ __forceinline__ void gload_lds16(const void* g, void* l) {
    __builtin_amdgcn_global_load_lds(
        (const __attribute__((address_space(1))) unsigned int*)g,
        (__attribute__((address_space(3))) unsigned int*)l, 16, 0, 0);
}

__global__ __launch_bounds__(256, 3)
void conv_gates_mfma_fast(const char* __restrict__ xT,
                          const ushort* __restrict__ wtab,
                          __half2* __restrict__ zf)
{
    __shared__ __align__(16) char slab[SLAB_BYTES];

    int p = blockIdx.x;
    int logical = (p & 7) * 496 + (p >> 3);   // XCD-aware
    int ht = logical & 31;
    int g  = logical >> 5;
    int d  = g % BD;
    int b  = g / BD;
    int h0 = ht * 4;

    int lane = threadIdx.x & 63;
    int wid  = threadIdx.x >> 6;
    int wl   = lane & 31;
    int cio  = (lane >> 5) * 16;

    // per-lane LDS read bases for dw=0,1,2 (swizzle folded in, wid row folded in)
    unsigned wc0 = (unsigned)(wl + 0);
    unsigned wc1 = (unsigned)(wl + 1);
    unsigned wc2 = (unsigned)(wl + 2);
    const char* bp0 = slab + wid * 4224 + ((wc0 * 32 + cio) ^ ((wc0 & 0xE) << 3));
    const char* bp1 = slab + wid * 4224 + ((wc1 * 32 + cio) ^ ((wc1 & 0xE) << 3));
    const char* bp2 = slab + wid * 4224 + ((wc2 * 32 + cio) ^ ((wc2 & 0xE) << 3));

    // zero edge regions: per row, bytes [0,32) (wcol 0) and [4128,4224)
    // (wcol 129..131). Visible after first __syncthreads.
    if (threadIdx.x < 192) {
        int r = threadIdx.x >> 5;
        int k = threadIdx.x & 31;
        int off = (k < 8) ? (k * 4) : (4128 + (k - 8) * 4);
        *(int*)(slab + r * 4224 + off) = 0;
    }

    f32x16 acc[4];
    #pragma unroll
    for (int n = 0; n < 4; ++n)
        #pragma unroll
        for (int r = 0; r < 16; ++r) acc[n][r] = 0.f;

    const bf16x8* wt = (const bf16x8*)wtab;

    #pragma unroll 1
    for (int kd = 0; kd < 3; ++kd) {
        int dd = d + kd - 1;
        if (dd < 0 || dd >= BD) continue;   // uniform per block

        // A-fragment prefetch: issue global loads before the barrier wait
        bf16x8 af[9];
        #pragma unroll
        for (int t = 0; t < 9; ++t)
            af[t] = wt[(kd * 9 + t) * 64 + lane];

        __syncthreads();   // previous slab fully consumed (+ zeroing visible)
        const char* plane = xT + ((size_t)(b * BD + dd) * 128) * 4096;
        for (int i = wid; i < 24; i += 4) {
            int r  = i >> 2;
            int ch = i & 3;
            int h  = h0 - 1 + r;
            char* dst = slab + r * 4224 + 32 + ch * 1024;
            if ((unsigned)h < HH) {
                const char* s = plane + (size_t)h * 4096 + ch * 1024 + lane * 16;
                gload_lds16(s, dst);
            } else {
                *(uint4*)(dst + lane * 16) = uint4{0, 0, 0, 0};
            }
        }
        __syncthreads();   // drains vmcnt -> slab ready

        // inner loop: row offset (t/3)*4224, dw base t%3, n offset n*1024 —
        // all compile-time immediates on ds_read_b128.
        #pragma unroll
        for (int t = 0; t < 9; ++t) {
            const char* base = (t % 3 == 0) ? bp0 : (t % 3 == 1) ? bp1 : bp2;
            const int roff = (t / 3) * 4224;
            #pragma unroll
            for (int n = 0; n < 4; ++n) {
                bf16x8 bfr = *(const bf16x8*)(base + roff + n * 1024);
                acc[n] = __builtin_amdgcn_mfma_f32_32x32x16_bf16(af[t], bfr, acc[n], 0, 0, 0);
            }
        }
    }

    // epilogue: point-major zf[bd][pt][c] half2. C/D map: col=lane&31,
    // row=(r&3)+8*(r>>2)+4*hi => r=0..3 -> c=co_hi+0..3 (contiguous),
    // r=4..7 -> c=8+co_hi+0..3. Two 16B stores per n-tile.
    int h = h0 + wid;
    int co_hi = 4 * (lane >> 5);
    size_t tbase = ((size_t)(b * BD + d) * PLANE + (size_t)h * WW);
    #pragma unroll
    for (int n = 0; n < 4; ++n) {
        int w = n * 32 + wl;
        __half2* pbase = zf + (tbase + w) * 16 + co_hi;
        union { uint4 u; __half2 h2[4]; } s0, s1;
        #pragma unroll
        for (int r = 0; r < 4; ++r) {
            s0.h2[r] = __floats2half2_rn(tanhf_fast(acc[n][r]),
                                         sigmoidf_fast(acc[n][r + 8]));
            s1.h2[r] = __floats2half2_rn(tanhf_fast(acc[n][r + 4]),
                                         sigmoidf_fast(acc[n][r + 12]));
        }
        *(uint4*)pbase       = s0.u;
        *(uint4*)(pbase + 8) = s1.u;
    }
}

// ---------------------------------------------------------------------------
// Conv fallback (reg staging from fp32; same point-major epilogue) — only if
// ws_size can't hold the 65MB bf16 buffer.
// ---------------------------------------------------------------------------
__global__ __launch_bounds__(256, 3)
void conv_gates_mfma(const float* __restrict__ inp,
                     const ushort* __restrict__ wtab,
                     __half2* __restrict__ zf)
{
    __shared__ __align__(16) char slab[SLAB_BYTES];

    int p = blockIdx.x;
    int logical = (p & 7) * 496 + (p >> 3);
    int ht = logical & 31;
    int g  = logical >> 5;
    int d  = g % BD;
    int b  = g / BD;
    int h0 = ht * 4;

    int lane = threadIdx.x & 63;
    int wid  = threadIdx.x >> 6;
    int wl   = lane & 31;
    int cio  = (lane >> 5) * 16;

    f32x16 acc[4];
    #pragma unroll
    for (int n = 0; n < 4; ++n)
        #pragma unroll
        for (int r = 0; r < 16; ++r) acc[n][r] = 0.f;

    const bf16x8* wt = (const bf16x8*)wtab;

    #pragma unroll 1
    for (int kd = 0; kd < 3; ++kd) {
        int dd = d + kd - 1;
        if (dd < 0 || dd >= BD) continue;

        __syncthreads();
        #pragma unroll 1
        for (int it = threadIdx.x; it < 6 * 132 * 4; it += 256) {
            int q    = it & 3;
            int rest = it >> 2;
            int wcol = rest % 132;
            int row  = rest / 132;
            int h = h0 + row - 1;
            int w = wcol - 1;
            float v0 = 0.f, v1 = 0.f, v2 = 0.f, v3 = 0.f;
            if ((unsigned)h < HH && (unsigned)w < WW) {
                const float* pin = inp
                    + ((size_t)(b * CIN + q * 4) * BD + dd) * PLANE + h * WW + w;
                v0 = pin[0];
                v1 = pin[CH_STRIDE];
                v2 = pin[2 * CH_STRIDE];
                v3 = pin[3 * CH_STRIDE];
            }
            uint2 pk;
            pk.x = (unsigned)f2bf(v0) | ((unsigned)f2bf(v1) << 16);
            pk.y = (unsigned)f2bf(v2) | ((unsigned)f2bf(v3) << 16);
            *(uint2*)(slab + slab_byte(row, wcol, q * 8)) = pk;
        }
        __syncthreads();

        bf16x8 af[9];
        #pragma unroll
        for (int t = 0; t < 9; ++t)
            af[t] = wt[(kd * 9 + t) * 64 + lane];

        #pragma unroll
        for (int t = 0; t < 9; ++t) {
            int dh = t / 3 - 1;
            int dw = t % 3 - 1;
            int row = wid + 1 + dh;
            #pragma unroll
            for (int n = 0; n < 4; ++n) {
                int wcol = n * 32 + wl + 1 + dw;
                bf16x8 bfr = *(const bf16x8*)(slab + slab_byte(row, wcol, cio));
                acc[n] = __builtin_amdgcn_mfma_f32_32x32x16_bf16(af[t], bfr, acc[n], 0, 0, 0);
            }
        }
    }

    int h = h0 + wid;
    int co_hi = 4 * (lane >> 5);
    size_t tbase = ((size_t)(b * BD + d) * PLANE + (size_t)h * WW);
    #pragma unroll
    for (int n = 0; n < 4; ++n) {
        int w = n * 32 + wl;
        __half2* pbase = zf + (tbase + w) * 16 + co_hi;
        union { uint4 u; __half2 h2[4]; } s0, s1;
        #pragma unroll
        for (int r = 0; r < 4; ++r) {
            s0.h2[r] = __floats2half2_rn(tanhf_fast(acc[n][r]),
                                         sigmoidf_fast(acc[n][r + 8]));
            s1.h2[r] = __floats2half2_rn(tanhf_fast(acc[n][r + 4]),
                                         sigmoidf_fast(acc[n][r + 12]));
        }
        *(uint4*)pbase       = s0.u;
        *(uint4*)(pbase + 8) = s1.u;
    }
}

// ---------------------------------------------------------------------------
// Scan over D. Thread = (b, pt, c): reads zf[bd][pt][c] half2 (coalesced),
// writes bf16 h into hbuf[bd][pt][c] (coalesced).
// ---------------------------------------------------------------------------
__global__ __launch_bounds__(256)
void scan_kernel(const __half2* __restrict__ zf, ushort* __restrict__ hbuf,
                 const int* __restrict__ rev_p)
{
    int tid = blockIdx.x * 256 + threadIdx.x;   // 4*16384*16 = 1,048,576
    int c   = tid & 15;
    int pt  = (tid >> 4) & 16383;
    int b   = tid >> 18;
    int rev = rev_p[0];

    const unsigned* zfw = (const unsigned*)zf;
    size_t col = ((size_t)b * BD) * PLANE * 16 + (size_t)pt * 16 + c;
    long long cur = (long long)col + (rev ? (long long)(BD - 1) * PLANE * 16 : 0);
    long long dstep = rev ? -(long long)PLANE * 16 : (long long)PLANE * 16;

    float h = 0.f;
    unsigned nz = zfw[cur];
    #pragma unroll 1
    for (int dd = 0; dd < BD; ++dd) {
        unsigned cz = nz;
        long long at = cur;
        cur += dstep;
        if (dd + 1 < BD) nz = zfw[cur];

        __half2 v = *(__half2*)&cz;
        float z = __low2float(v);
        float f = __high2float(v);
        h = f * h + (1.f - f) * z;
        hbuf[at] = f2bf(h);
    }
}

// ---------------------------------------------------------------------------
// MLP via MFMA (unchanged). Wave = 32 points; B-frag = one 16B hbuf load.
// ---------------------------------------------------------------------------
__global__ __launch_bounds__(256)
void mlp_mfma_kernel(const char* __restrict__ hbuf,
                     const ushort* __restrict__ wtab2,
                     float* __restrict__ out)
{
    int lane = threadIdx.x & 63;
    int wid  = threadIdx.x >> 6;
    int p    = lane & 31;
    int hi   = lane >> 5;

    size_t tile = (size_t)blockIdx.x * 4 + wid;   // 63488 tiles of 32 points
    size_t ptg  = tile * 32 + p;

    const bf16x8* W = (const bf16x8*)wtab2;
    bf16x8 af1  = W[lane];
    bf16x8 af2a = W[64 + lane];
    bf16x8 af2b = W[128 + lane];
    bf16x8 af3  = W[192 + lane];
    bf16x8 bx   = *(const bf16x8*)(hbuf + ptg * 32 + hi * 16);

    f32x16 zacc;
    #pragma unroll
    for (int r = 0; r < 16; ++r) zacc[r] = 0.f;

    f32x16 acc1 = __builtin_amdgcn_mfma_f32_32x32x16_bf16(af1, bx, zacc, 0, 0, 0);
    f32x16 acc3 = __builtin_amdgcn_mfma_f32_32x32x16_bf16(af3, bx, zacc, 0, 0, 0);

    union { bf16x8 v; unsigned u[4]; } b2a, b2b;
    #pragma unroll
    for (int q = 0; q < 4; ++q) {
        float g0 = gelu_as(acc1[2 * q]);
        float g1 = gelu_as(acc1[2 * q + 1]);
        float g8 = gelu_as(acc1[8 + 2 * q]);
        float g9 = gelu_as(acc1[8 + 2 * q + 1]);
        b2a.u[q] = (unsigned)f2bf(g0) | ((unsigned)f2bf(g1) << 16);
        b2b.u[q] = (unsigned)f2bf(g8) | ((unsigned)f2bf(g9) << 16);
    }

    f32x16 acc2 = __builtin_amdgcn_mfma_f32_32x32x16_bf16(af2a, b2a.v, zacc, 0, 0, 0);
    acc2 = __builtin_amdgcn_mfma_f32_32x32x16_bf16(af2b, b2b.v, acc2, 0, 0, 0);

    int bd  = (int)(ptg >> 14);
    int pix = (int)(ptg & 16383);
    int b   = bd / BD;
    int d   = bd % BD;
    float* obase = out + (size_t)b * HC * CH_STRIDE + (size_t)d * PLANE + pix;

    #pragma unroll
    for (int r = 0; r < 8; ++r) {
        int c = (r & 3) + 8 * (r >> 2) + 4 * hi;
        float y = acc2[r] + acc3[r] * sigmoidf_fast(acc3[r + 8]);
        obase[(size_t)c * CH_STRIDE] = y;
    }
}

extern "C" void kernel_launch(void* const* d_in, const int* in_sizes, int n_in,
                              void* d_out, int out_size, void* d_ws, size_t ws_size,
                              hipStream_t stream)
{
    const float* inp = (const float*)d_in[0];
    const float* cw  = (const float*)d_in[1];
    const float* w1  = (const float*)d_in[2];
    const float* w2  = (const float*)d_in[3];
    const float* w3  = (const float*)d_in[4];
    const int*   rev = (const int*)d_in[5];

    ushort* wtab  = (ushort*)d_ws;                    // [0, 27648)
    ushort* wtab2 = (ushort*)((char*)d_ws + 27648);   // [27648, 31744)
    char*   xT    = (char*)d_ws + 32768;              // 65 MB (xprep/conv)
    ushort* hbuf  = (ushort*)xT;                      // reused after conv
    const size_t need = 32768 + (size_t)4 * BD * 128 * 4096;

    wprep_kernel<<<dim3(54), dim3(256), 0, stream>>>(cw, wtab);
    wprep2_kernel<<<dim3(8), dim3(256), 0, stream>>>(w1, w2, w3, wtab2);

    if (ws_size >= need) {
        xprep_kernel<<<dim3(7936), dim3(256), 0, stream>>>(inp, xT);
        conv_gates_mfma_fast<<<dim3(3968), dim3(256), 0, stream>>>(
            xT, wtab, (__half2*)d_out);
    } else {
        conv_gates_mfma<<<dim3(3968), dim3(256), 0, stream>>>(
            inp, wtab, (__half2*)d_out);
    }

    scan_kernel<<<dim3(4096), dim3(256), 0, stream>>>(
        (const __half2*)d_out, hbuf, rev);

    mlp_mfma_kernel<<<dim3(15872), dim3(256), 0, stream>>>(
        (const char*)hbuf, wtab2, (float*)d_out);
}

// Round 7
// 204.464 us; speedup vs baseline: 44.4981x; 1.0438x over previous
//
#include <hip/hip_runtime.h>
#include <hip/hip_fp16.h>

#define HC 16
#define CIN 16
#define BD 31
#define HH 128
#define WW 128
#define PLANE (HH*WW)           // 16384
#define CH_STRIDE (BD*PLANE)    // 507904

typedef __attribute__((ext_vector_type(8))) short bf16x8;   // 8 bf16 = 4 VGPR
typedef __attribute__((ext_vector_type(16))) float f32x16;  // MFMA 32x32 acc

__device__ __forceinline__ float sigmoidf_fast(float x) {
    return 1.0f / (1.0f + __expf(-x));
}
__device__ __forceinline__ float tanhf_fast(float x) {
    return 2.0f / (1.0f + __expf(-2.0f * x)) - 1.0f;
}
__device__ __forceinline__ ushort f2bf(float f) {   // RNE float->bf16
    unsigned u = __float_as_uint(f);
    u = (u + 0x7fffu + ((u >> 16) & 1u)) >> 16;
    return (ushort)u;
}
// exact-gelu via Abramowitz-Stegun 7.1.26 erf (|eps|<=1.5e-7)
__device__ __forceinline__ float gelu_as(float s) {
    float z  = 0.70710678118f * s;
    float az = fabsf(z);
    float t  = __builtin_amdgcn_rcpf(fmaf(0.3275911f, az, 1.0f));
    float p  = t * (0.254829592f + t * (-0.284496736f + t * (1.421413741f
             + t * (-1.453152027f + t * 1.061405429f))));
    float e  = __expf(-z * z);
    float er = copysignf(1.0f - p * e, z);
    return 0.5f * s * (1.0f + er);
}

// ---------------------------------------------------------------------------
// Conv weight prep: wtab[kd][tap][lane][j] (bf16): co=lane&31, ci=8*(lane>>5)+j.
// ---------------------------------------------------------------------------
__global__ void wprep_kernel(const float* __restrict__ cw, ushort* __restrict__ wtab)
{
    int idx = blockIdx.x * 256 + threadIdx.x;
    if (idx >= 3 * 9 * 64 * 8) return;
    int j    = idx & 7;
    int lane = (idx >> 3) & 63;
    int t    = (idx >> 9) % 9;
    int kd   = (idx >> 9) / 9;
    int co = lane & 31;
    int ci = 8 * (lane >> 5) + j;
    int kh = t / 3, kw = t % 3;
    wtab[idx] = f2bf(cw[(co * CIN + ci) * 27 + kd * 9 + kh * 3 + kw]);
}

// ---------------------------------------------------------------------------
// MLP weight prep: 4 fragment tables x 64 lanes x 8 bf16.
// tbl0: w1^T A-frag; tbl1/2: w2 A-frags (permuted k, rows>=16 zero);
// tbl3: w3^T A-frag ([a|wg] rows). Shared-k-permutation with the B side.
// ---------------------------------------------------------------------------
__global__ void wprep2_kernel(const float* __restrict__ w1,
                              const float* __restrict__ w2,
                              const float* __restrict__ w3,
                              ushort* __restrict__ wtab2)
{
    int idx = blockIdx.x * 256 + threadIdx.x;
    if (idx >= 2048) return;
    int e    = idx & 7;
    int lane = (idx >> 3) & 63;
    int tbl  = idx >> 9;
    int m  = lane & 31;
    int hi = lane >> 5;
    float v = 0.f;
    if (tbl == 0)      v = w1[(8 * hi + e) * 32 + m];
    else if (tbl == 3) v = w3[(8 * hi + e) * 32 + m];
    else {
        int mf = tbl - 1;
        if (m < 16) v = w2[((e & 3) + 8 * (e >> 2) + 4 * hi + 16 * mf) * 16 + m];
    }
    wtab2[idx] = f2bf(v);
}

// ---------------------------------------------------------------------------
// Slab swizzle: byte = (row*4224 + wcol*32 + cio) ^ ((wcol&0xE)<<3). Injective,
// bank-conflict-free (measured 0). n*1024 / half*2048 / row*4224 offsets leave
// bits 1-3 of wcol and the XOR untouched.
// ---------------------------------------------------------------------------
#define SLAB_BYTES (4 * 4224)   // 16896 B (4 input rows for a 2-row tile)

// ---------------------------------------------------------------------------
// xprep: fp32 [b][ci][d][h][w] -> bf16 rows xT[b][d][h][4096B], ci innermost,
// slab swizzle pre-baked (swizzle-source + linear gload_lds dest, rule #21).
// ---------------------------------------------------------------------------
__global__ __launch_bounds__(256)
void xprep_kernel(const float* __restrict__ inp, char* __restrict__ xT)
{
    __shared__ float tile[16][256];
    int t  = threadIdx.x;
    int hp = blockIdx.x & 63;
    int g  = blockIdx.x >> 6;
    int d  = g % BD;
    int b  = g / BD;

    size_t src = (size_t)b * CIN * CH_STRIDE + (size_t)d * PLANE + hp * 256;
    #pragma unroll
    for (int c = 0; c < 16; ++c)
        tile[c][t] = inp[src + (size_t)c * CH_STRIDE + t];
    __syncthreads();

    int w  = t & 127;
    int rr = t >> 7;
    char* rowp = xT + (((size_t)(b * BD + d) * 128) + hp * 2 + rr) * 4096;
    #pragma unroll
    for (int q = 0; q < 2; ++q) {
        uint4 pk;
        pk.x = (unsigned)f2bf(tile[q*8+0][t]) | ((unsigned)f2bf(tile[q*8+1][t]) << 16);
        pk.y = (unsigned)f2bf(tile[q*8+2][t]) | ((unsigned)f2bf(tile[q*8+3][t]) << 16);
        pk.z = (unsigned)f2bf(tile[q*8+4][t]) | ((unsigned)f2bf(tile[q*8+5][t]) << 16);
        pk.w = (unsigned)f2bf(tile[q*8+6][t]) | ((unsigned)f2bf(tile[q*8+7][t]) << 16);
        unsigned off = ((unsigned)((w + 1) * 32 + q * 16) ^ (((unsigned)(w + 1) & 0xE) << 3)) - 32;
        *(uint4*)(rowp + off) = pk;
    }
}

// ---------------------------------------------------------------------------
// Conv via MFMA. Block = 256 thr (4 waves), tile = 2 H-rows x 128 W for one
// (b,d). Wave (row=wid>>1, half=wid&1) owns 2 n-tiles -> 32 AGPR acc (was 64:
// reg pressure capped occupancy at 3 waves/SIMD; now 4+ under (256,4)).
// Slab = 4 rows (h0-1..h0+2), staged via gload_lds from pre-swizzled xT.
// ---------------------------------------------------------------------------
__device__ __forceinline__ void gload_lds16(const void* g, void* l) {
    __builtin_amdgcn_global_load_lds(
        (const __attribute__((address_space(1))) unsigned int*)g,
        (__attribute__((address_space(3))) unsigned int*)l, 16, 0, 0);
}

__global__ __launch_bounds__(256, 4)
void conv_gates_mfma_fast(const char* __restrict__ xT,
                          const ushort* __restrict__ wtab,
                          __half2* __restrict__ zf)
{
    __shared__ __align__(16) char slab[SLAB_BYTES];

    // grid 7936 = 8 XCD * 992: consecutive logical ids share an XCD's L2
    int p = blockIdx.x;
    int logical = (p & 7) * 992 + (p >> 3);
    int ht = logical & 63;          // 64 h-tiles of 2 rows
    int g  = logical >> 6;
    int d  = g % BD;
    int b  = g / BD;
    int h0 = ht * 2;

    int lane = threadIdx.x & 63;
    int wid  = threadIdx.x >> 6;
    int row  = wid >> 1;            // 0..1: output row within tile
    int half = wid & 1;             // 0..1: w-half (n = 2*half + nn)
    int wl   = lane & 31;
    int cio  = (lane >> 5) * 16;

    // per-lane LDS read bases for dw=0,1,2; row/half folded in.
    // wcol = 64*half + nn*32 + wl + dw; 64*half and nn*32 don't touch the
    // XOR bits => handled as +2048*half / +1024*nn immediates.
    const char* bp[3];
    #pragma unroll
    for (int dw = 0; dw < 3; ++dw) {
        unsigned wc = (unsigned)(wl + dw);
        bp[dw] = slab + row * 4224 + half * 2048
               + ((wc * 32 + cio) ^ ((wc & 0xE) << 3));
    }

    // zero edge regions: per row, bytes [0,32) (wcol 0) and [4128,4224).
    if (threadIdx.x < 128) {
        int r = threadIdx.x >> 5;
        int k = threadIdx.x & 31;
        int off = (k < 8) ? (k * 4) : (4128 + (k - 8) * 4);
        *(int*)(slab + r * 4224 + off) = 0;
    }

    f32x16 acc[2];
    #pragma unroll
    for (int n = 0; n < 2; ++n)
        #pragma unroll
        for (int r = 0; r < 16; ++r) acc[n][r] = 0.f;

    const bf16x8* wt = (const bf16x8*)wtab;

    #pragma unroll 1
    for (int kd = 0; kd < 3; ++kd) {
        int dd = d + kd - 1;
        if (dd < 0 || dd >= BD) continue;   // uniform per block

        // A-fragment prefetch before the barrier wait
        bf16x8 af[9];
        #pragma unroll
        for (int t = 0; t < 9; ++t)
            af[t] = wt[(kd * 9 + t) * 64 + lane];

        __syncthreads();   // previous slab fully consumed (+ zeroing visible)
        const char* plane = xT + ((size_t)(b * BD + dd) * 128) * 4096;
        // 16 x 1KB copies (4 rows x 4 chunks), 4 per wave
        for (int i = wid; i < 16; i += 4) {
            int r  = i >> 2;
            int ch = i & 3;
            int h  = h0 - 1 + r;
            char* dst = slab + r * 4224 + 32 + ch * 1024;
            if ((unsigned)h < HH) {
                const char* s = plane + (size_t)h * 4096 + ch * 1024 + lane * 16;
                gload_lds16(s, dst);
            } else {
                *(uint4*)(dst + lane * 16) = uint4{0, 0, 0, 0};
            }
        }
        __syncthreads();   // drains vmcnt -> slab ready

        // input row for tap dh = row + dh (slab row 0 = h0-1)
        #pragma unroll
        for (int t = 0; t < 9; ++t) {
            const char* base = bp[t % 3];
            const int roff = (t / 3) * 4224;
            #pragma unroll
            for (int nn = 0; nn < 2; ++nn) {
                bf16x8 bfr = *(const bf16x8*)(base + roff + nn * 1024);
                acc[nn] = __builtin_amdgcn_mfma_f32_32x32x16_bf16(af[t], bfr, acc[nn], 0, 0, 0);
            }
        }
    }

    // epilogue: point-major zf[bd][pt][c] half2. C/D map: col=lane&31,
    // row=(r&3)+8*(r>>2)+4*hi => contiguous c-quads -> 2x16B stores per tile.
    int h = h0 + row;
    int co_hi = 4 * (lane >> 5);
    size_t tbase = ((size_t)(b * BD + d) * PLANE + (size_t)h * WW);
    #pragma unroll
    for (int nn = 0; nn < 2; ++nn) {
        int w = (2 * half + nn) * 32 + wl;
        __half2* pbase = zf + (tbase + w) * 16 + co_hi;
        union { uint4 u; __half2 h2[4]; } s0, s1;
        #pragma unroll
        for (int r = 0; r < 4; ++r) {
            s0.h2[r] = __floats2half2_rn(tanhf_fast(acc[nn][r]),
                                         sigmoidf_fast(acc[nn][r + 8]));
            s1.h2[r] = __floats2half2_rn(tanhf_fast(acc[nn][r + 4]),
                                         sigmoidf_fast(acc[nn][r + 12]));
        }
        *(uint4*)pbase       = s0.u;
        *(uint4*)(pbase + 8) = s1.u;
    }
}

// ---------------------------------------------------------------------------
// FUSED scan+MLP. Wave = 32 points; lane (p,hi) owns channels 8hi..8hi+7 of
// point p — exactly the MLP B-frag layout, so h never leaves registers.
// Per d: load zf (32B/lane, contiguous 2KB/wave), scan-update 8 ch, pack to
// bf16x8, 4 MFMAs + gelu, write 8 out floats. Next-d zf prefetched.
// ---------------------------------------------------------------------------
__global__ __launch_bounds__(256)
void scanmlp_kernel(const __half2* __restrict__ zf,
                    const ushort* __restrict__ wtab2,
                    float* __restrict__ out,
                    const int* __restrict__ rev_p)
{
    int lane = threadIdx.x & 63;
    int wid  = threadIdx.x >> 6;
    int p    = lane & 31;
    int hi   = lane >> 5;
    int rev  = rev_p[0];

    size_t gw  = (size_t)blockIdx.x * 4 + wid;   // 2048 waves
    size_t ptg = gw * 32 + p;                    // global point 0..65535
    int b   = (int)(ptg >> 14);
    int pix = (int)(ptg & 16383);

    const bf16x8* W = (const bf16x8*)wtab2;
    bf16x8 af1  = W[lane];
    bf16x8 af2a = W[64 + lane];
    bf16x8 af2b = W[128 + lane];
    bf16x8 af3  = W[192 + lane];

    const char* zbase = (const char*)zf
        + ((size_t)(b * BD) * PLANE + pix) * 64 + hi * 32;
    long long dstep = (long long)PLANE * 64;
    long long cur   = rev ? (long long)(BD - 1) * dstep : 0;
    long long sgn   = rev ? -dstep : dstep;

    float* obase0 = out + (size_t)b * HC * CH_STRIDE + pix;

    float h[8];
    #pragma unroll
    for (int j = 0; j < 8; ++j) h[j] = 0.f;

    f32x16 zacc;
    #pragma unroll
    for (int r = 0; r < 16; ++r) zacc[r] = 0.f;

    uint4 nz0 = *(const uint4*)(zbase + cur);
    uint4 nz1 = *(const uint4*)(zbase + cur + 16);

    #pragma unroll 1
    for (int dd = 0; dd < BD; ++dd) {
        unsigned zw[8] = {nz0.x, nz0.y, nz0.z, nz0.w,
                          nz1.x, nz1.y, nz1.z, nz1.w};
        int d = rev ? (BD - 1 - dd) : dd;
        cur += sgn;
        if (dd + 1 < BD) {
            nz0 = *(const uint4*)(zbase + cur);
            nz1 = *(const uint4*)(zbase + cur + 16);
        }

        // scan update + B-frag pack
        union { bf16x8 v; unsigned u[4]; } bx;
        #pragma unroll
        for (int j = 0; j < 8; ++j) {
            __half2 v = *(__half2*)&zw[j];
            float z = __low2float(v);
            float f = __high2float(v);
            h[j] = f * h[j] + (1.f - f) * z;
        }
        #pragma unroll
        for (int q = 0; q < 4; ++q)
            bx.u[q] = (unsigned)f2bf(h[2 * q]) | ((unsigned)f2bf(h[2 * q + 1]) << 16);

        f32x16 acc1 = __builtin_amdgcn_mfma_f32_32x32x16_bf16(af1, bx.v, zacc, 0, 0, 0);
        f32x16 acc3 = __builtin_amdgcn_mfma_f32_32x32x16_bf16(af3, bx.v, zacc, 0, 0, 0);

        union { bf16x8 v; unsigned u[4]; } b2a, b2b;
        #pragma unroll
        for (int q = 0; q < 4; ++q) {
            float g0 = gelu_as(acc1[2 * q]);
            float g1 = gelu_as(acc1[2 * q + 1]);
            float g8 = gelu_as(acc1[8 + 2 * q]);
            float g9 = gelu_as(acc1[8 + 2 * q + 1]);
            b2a.u[q] = (unsigned)f2bf(g0) | ((unsigned)f2bf(g1) << 16);
            b2b.u[q] = (unsigned)f2bf(g8) | ((unsigned)f2bf(g9) << 16);
        }

        f32x16 acc2 = __builtin_amdgcn_mfma_f32_32x32x16_bf16(af2a, b2a.v, zacc, 0, 0, 0);
        acc2 = __builtin_amdgcn_mfma_f32_32x32x16_bf16(af2b, b2b.v, acc2, 0, 0, 0);

        float* ob = obase0 + (size_t)d * PLANE;
        #pragma unroll
        for (int r = 0; r < 8; ++r) {
            int c = (r & 3) + 8 * (r >> 2) + 4 * hi;
            ob[(size_t)c * CH_STRIDE] = acc2[r] + acc3[r] * sigmoidf_fast(acc3[r + 8]);
        }
    }
}

// ---------------------------------------------------------------------------
// Fallback pair (used when ws can't hold the 130MB zf buffer): scan d_out(zf)
// -> hbuf(bf16), then MLP hbuf -> d_out. Identical numerics to fused path.
// ---------------------------------------------------------------------------
__global__ __launch_bounds__(256)
void scan_kernel(const __half2* __restrict__ zf, ushort* __restrict__ hbuf,
                 const int* __restrict__ rev_p)
{
    int tid = blockIdx.x * 256 + threadIdx.x;
    int c   = tid & 15;
    int pt  = (tid >> 4) & 16383;
    int b   = tid >> 18;
    int rev = rev_p[0];

    const unsigned* zfw = (const unsigned*)zf;
    size_t col = ((size_t)b * BD) * PLANE * 16 + (size_t)pt * 16 + c;
    long long cur = (long long)col + (rev ? (long long)(BD - 1) * PLANE * 16 : 0);
    long long dstep = rev ? -(long long)PLANE * 16 : (long long)PLANE * 16;

    float h = 0.f;
    unsigned nz = zfw[cur];
    #pragma unroll 1
    for (int dd = 0; dd < BD; ++dd) {
        unsigned cz = nz;
        long long at = cur;
        cur += dstep;
        if (dd + 1 < BD) nz = zfw[cur];

        __half2 v = *(__half2*)&cz;
        float z = __low2float(v);
        float f = __high2float(v);
        h = f * h + (1.f - f) * z;
        hbuf[at] = f2bf(h);
    }
}

__global__ __launch_bounds__(256)
void mlp_mfma_kernel(const char* __restrict__ hbuf,
                     const ushort* __restrict__ wtab2,
                     float* __restrict__ out)
{
    int lane = threadIdx.x & 63;
    int wid  = threadIdx.x >> 6;
    int p    = lane & 31;
    int hi   = lane >> 5;

    size_t tile = (size_t)blockIdx.x * 4 + wid;
    size_t ptg  = tile * 32 + p;

    const bf16x8* W = (const bf16x8*)wtab2;
    bf16x8 af1  = W[lane];
    bf16x8 af2a = W[64 + lane];
    bf16x8 af2b = W[128 + lane];
    bf16x8 af3  = W[192 + lane];
    bf16x8 bx   = *(const bf16x8*)(hbuf + ptg * 32 + hi * 16);

    f32x16 zacc;
    #pragma unroll
    for (int r = 0; r < 16; ++r) zacc[r] = 0.f;

    f32x16 acc1 = __builtin_amdgcn_mfma_f32_32x32x16_bf16(af1, bx, zacc, 0, 0, 0);
    f32x16 acc3 = __builtin_amdgcn_mfma_f32_32x32x16_bf16(af3, bx, zacc, 0, 0, 0);

    union { bf16x8 v; unsigned u[4]; } b2a, b2b;
    #pragma unroll
    for (int q = 0; q < 4; ++q) {
        float g0 = gelu_as(acc1[2 * q]);
        float g1 = gelu_as(acc1[2 * q + 1]);
        float g8 = gelu_as(acc1[8 + 2 * q]);
        float g9 = gelu_as(acc1[8 + 2 * q + 1]);
        b2a.u[q] = (unsigned)f2bf(g0) | ((unsigned)f2bf(g1) << 16);
        b2b.u[q] = (unsigned)f2bf(g8) | ((unsigned)f2bf(g9) << 16);
    }

    f32x16 acc2 = __builtin_amdgcn_mfma_f32_32x32x16_bf16(af2a, b2a.v, zacc, 0, 0, 0);
    acc2 = __builtin_amdgcn_mfma_f32_32x32x16_bf16(af2b, b2b.v, acc2, 0, 0, 0);

    int bd  = (int)(ptg >> 14);
    int pix = (int)(ptg & 16383);
    int b   = bd / BD;
    int d   = bd % BD;
    float* obase = out + (size_t)b * HC * CH_STRIDE + (size_t)d * PLANE + pix;

    #pragma unroll
    for (int r = 0; r < 8; ++r) {
        int c = (r & 3) + 8 * (r >> 2) + 4 * hi;
        float y = acc2[r] + acc3[r] * sigmoidf_fast(acc3[r + 8]);
        obase[(size_t)c * CH_STRIDE] = y;
    }
}

extern "C" void kernel_launch(void* const* d_in, const int* in_sizes, int n_in,
                              void* d_out, int out_size, void* d_ws, size_t ws_size,
                              hipStream_t stream)
{
    const float* inp = (const float*)d_in[0];
    const float* cw  = (const float*)d_in[1];
    const float* w1  = (const float*)d_in[2];
    const float* w2  = (const float*)d_in[3];
    const float* w3  = (const float*)d_in[4];
    const int*   rev = (const int*)d_in[5];

    ushort* wtab  = (ushort*)d_ws;                    // [0, 27648)
    ushort* wtab2 = (ushort*)((char*)d_ws + 27648);   // [27648, 31744)
    char*   xT    = (char*)d_ws + 32768;              // 65,011,712 B

    const size_t xt_bytes = (size_t)4 * BD * 128 * 4096;
    const size_t zf_off   = 32768 + xt_bytes;                   // 65,044,480
    const size_t zf_bytes = (size_t)4 * BD * PLANE * 16 * 4;    // 130,023,424
    const bool fused = (ws_size >= zf_off + zf_bytes);

    __half2* zfp = fused ? (__half2*)((char*)d_ws + zf_off) : (__half2*)d_out;

    wprep_kernel<<<dim3(54), dim3(256), 0, stream>>>(cw, wtab);
    wprep2_kernel<<<dim3(8), dim3(256), 0, stream>>>(w1, w2, w3, wtab2);

    xprep_kernel<<<dim3(7936), dim3(256), 0, stream>>>(inp, xT);

    // 4b * 31d * 64 h-tiles = 7936 blocks (2 rows x 128 w each)
    conv_gates_mfma_fast<<<dim3(7936), dim3(256), 0, stream>>>(
        xT, wtab, zfp);

    if (fused) {
        // 65536 points / (4 waves * 32 points) = 512 blocks
        scanmlp_kernel<<<dim3(512), dim3(256), 0, stream>>>(
            zfp, wtab2, (float*)d_out, rev);
    } else {
        ushort* hbuf = (ushort*)xT;   // reuse xT region after conv
        scan_kernel<<<dim3(4096), dim3(256), 0, stream>>>(
            (const __half2*)d_out, hbuf, rev);
        mlp_mfma_kernel<<<dim3(15872), dim3(256), 0, stream>>>(
            (const char*)hbuf, wtab2, (float*)d_out);
    }
}